// Round 1
// baseline (1829.718 us; speedup 1.0000x reference)
//
#include <hip/hip_runtime.h>
#include <cstdint>
#include <cstddef>

// Problem constants (B=2, C=256, H=W=96, K=3, O=256, offset channels=27)
#define BATCH 2
#define HH 96
#define WW 96
#define CC 256
#define OCOFF 27
#define KKP 9
#define TP 8          // pixels per block (along w)
#define CCH 128       // channels per LDS chunk
#define KCH (CCH*KKP) // 1152 k-values per chunk

// ---------------------------------------------------------------------------
// Weight transpose: w[o][c][ki][kj] -> wT[k=c*9+ki*3+kj][o]
// ---------------------------------------------------------------------------
__global__ __launch_bounds__(256) void transpose_w_kernel(const float* __restrict__ w,
                                                          float* __restrict__ wT) {
    int idx = blockIdx.x * 256 + threadIdx.x;   // 0 .. 256*2304-1
    int o = idx & 255;
    int k = idx >> 8;                           // c*9 + kk
    wT[idx] = w[o * 2304 + k];
}

// ---------------------------------------------------------------------------
// Offset/mask conv: standard 3x3, pad 1, bias. One thread per (b,o,h,w).
// om layout: [B][27][H][W]
// ---------------------------------------------------------------------------
__global__ __launch_bounds__(256) void offconv_kernel(const float* __restrict__ in,
                                                      const float* __restrict__ woff,
                                                      const float* __restrict__ boff,
                                                      float* __restrict__ om) {
    int idx = blockIdx.x * 256 + threadIdx.x;   // B*27*96*96 total
    int w = idx % WW;
    int h = (idx / WW) % HH;
    int o = (idx / (HH * WW)) % OCOFF;
    int b = idx / (HH * WW * OCOFF);

    float acc = boff[o];

    int  yy[3], xx[3];
    bool yv[3], xv[3];
#pragma unroll
    for (int t = 0; t < 3; ++t) {
        yy[t] = h + t - 1; yv[t] = ((unsigned)yy[t] < (unsigned)HH);
        xx[t] = w + t - 1; xv[t] = ((unsigned)xx[t] < (unsigned)WW);
    }

    const float* wp = woff + (size_t)o * (CC * 9);
    const float* ip = in + (size_t)b * CC * HH * WW;

    for (int c = 0; c < CC; ++c) {
        const float* pc = ip + (size_t)c * HH * WW;
        const float* wc = wp + c * 9;
#pragma unroll
        for (int ki = 0; ki < 3; ++ki) {
#pragma unroll
            for (int kj = 0; kj < 3; ++kj) {
                float xval = (yv[ki] && xv[kj]) ? pc[yy[ki] * WW + xx[kj]] : 0.0f;
                acc = fmaf(wc[ki * 3 + kj], xval, acc);
            }
        }
    }
    om[idx] = acc;
}

// ---------------------------------------------------------------------------
// Fused deformable sampling + GEMM + ReLU.
// One block = 8 consecutive pixels (same row) x all 256 output channels.
// Phase 1: bilinear sample (mask-premultiplied) 128-channel chunk -> LDS.
// Phase 2: out[o][p] += sum_k wT[k][o] * s[k][p]  (weights coalesced,
//          LDS reads broadcast).
// ---------------------------------------------------------------------------
__global__ __launch_bounds__(256) void dfconv_kernel(const float* __restrict__ in,
                                                     const float* __restrict__ om,
                                                     const float* __restrict__ wT,
                                                     float* __restrict__ out) {
    __shared__ float s[KCH * TP];               // 9216 floats = 36 KB
    __shared__ int   gy[KKP * TP];
    __shared__ int   gx[KKP * TP];
    __shared__ float gw[KKP * TP][4];

    const int tile = blockIdx.x;                // B*96*12 tiles
    const int w0 = (tile % (WW / TP)) * TP;
    const int h  = (tile / (WW / TP)) % HH;
    const int b  = tile / ((WW / TP) * HH);
    const int t  = threadIdx.x;

    // Precompute per-(tap, pixel) geometry + mask-scaled bilinear weights.
    if (t < KKP * TP) {
        int p  = t & (TP - 1);
        int kk = t / TP;
        int base = ((b * OCOFF) * HH + h) * WW + w0 + p;
        float dy = om[base + (2 * kk) * (HH * WW)];
        float dx = om[base + (2 * kk + 1) * (HH * WW)];
        float mv = om[base + (2 * KKP + kk) * (HH * WW)];
        float m  = 1.0f / (1.0f + expf(-mv));

        float ys = (float)(h + kk / 3 - 1) + dy;
        float xs = (float)(w0 + p + kk % 3 - 1) + dx;
        float fy = floorf(ys), fx = floorf(xs);
        int iy = (int)fy, ix = (int)fx;
        float wy1 = ys - fy, wx1 = xs - fx;
        float wy0 = 1.0f - wy1, wx0 = 1.0f - wx1;
        gy[t] = iy;
        gx[t] = ix;
        gw[t][0] = m * wy0 * wx0;
        gw[t][1] = m * wy0 * wx1;
        gw[t][2] = m * wy1 * wx0;
        gw[t][3] = m * wy1 * wx1;
    }
    __syncthreads();

    float acc[TP];
#pragma unroll
    for (int p = 0; p < TP; ++p) acc[p] = 0.0f;

    const int o = t;

    for (int chunk = 0; chunk < CC / CCH; ++chunk) {
        // ---- Phase 1: sample chunk into LDS (linear write addresses) ----
        for (int i = 0; i < (CCH * KKP * TP) / 256; ++i) {   // 36 iters
            int task = t + 256 * i;
            int p  = task & (TP - 1);
            int kl = task >> 3;                 // 0..1151 (c_local*9+kk)
            int cl = kl / 9;
            int kk = kl - cl * 9;
            int c  = chunk * CCH + cl;
            int g  = kk * TP + p;

            int iy = gy[g], ix = gx[g];
            const float* base = in + ((size_t)(b * CC + c) * HH) * WW;

            int y0 = min(max(iy, 0), HH - 1);
            int y1 = min(max(iy + 1, 0), HH - 1);
            int x0 = min(max(ix, 0), WW - 1);
            int x1 = min(max(ix + 1, 0), WW - 1);
            bool yv0 = ((unsigned)iy < (unsigned)HH);
            bool yv1 = ((unsigned)(iy + 1) < (unsigned)HH);
            bool xv0 = ((unsigned)ix < (unsigned)WW);
            bool xv1 = ((unsigned)(ix + 1) < (unsigned)WW);

            float v00 = (yv0 && xv0) ? base[y0 * WW + x0] : 0.0f;
            float v01 = (yv0 && xv1) ? base[y0 * WW + x1] : 0.0f;
            float v10 = (yv1 && xv0) ? base[y1 * WW + x0] : 0.0f;
            float v11 = (yv1 && xv1) ? base[y1 * WW + x1] : 0.0f;

            s[task] = gw[g][0] * v00 + gw[g][1] * v01 +
                      gw[g][2] * v10 + gw[g][3] * v11;
        }
        __syncthreads();

        // ---- Phase 2: GEMM over this chunk ----
        const float* wp = wT + (size_t)(chunk * KCH) * 256 + o;
#pragma unroll 4
        for (int kl = 0; kl < KCH; ++kl) {
            float wv = wp[(size_t)kl * 256];
            const float4* sp = reinterpret_cast<const float4*>(s + kl * TP);
            float4 a0 = sp[0];
            float4 a1 = sp[1];
            acc[0] = fmaf(wv, a0.x, acc[0]);
            acc[1] = fmaf(wv, a0.y, acc[1]);
            acc[2] = fmaf(wv, a0.z, acc[2]);
            acc[3] = fmaf(wv, a0.w, acc[3]);
            acc[4] = fmaf(wv, a1.x, acc[4]);
            acc[5] = fmaf(wv, a1.y, acc[5]);
            acc[6] = fmaf(wv, a1.z, acc[6]);
            acc[7] = fmaf(wv, a1.w, acc[7]);
        }
        __syncthreads();
    }

    // ---- Epilogue: ReLU + store ----
    float* op = out + (((size_t)(b * CC + o) * HH) + h) * WW + w0;
#pragma unroll
    for (int p = 0; p < TP; ++p) op[p] = fmaxf(acc[p], 0.0f);
}

// ---------------------------------------------------------------------------
extern "C" void kernel_launch(void* const* d_in, const int* in_sizes, int n_in,
                              void* d_out, int out_size, void* d_ws, size_t ws_size,
                              hipStream_t stream) {
    const float* x     = (const float*)d_in[0];
    const float* woff0 = (const float*)d_in[1];
    const float* boff0 = (const float*)d_in[2];
    const float* w0    = (const float*)d_in[3];
    const float* woff1 = (const float*)d_in[4];
    const float* boff1 = (const float*)d_in[5];
    const float* w1    = (const float*)d_in[6];
    float* out = (float*)d_out;

    // Workspace layout (floats): om [2*27*96*96], h1 [2*256*96*96],
    // wT0 [2304*256], wT1 [2304*256]  => ~25.6 MB total.
    float* om  = (float*)d_ws;
    float* h1  = om + (size_t)BATCH * OCOFF * HH * WW;
    float* wT0 = h1 + (size_t)BATCH * CC * HH * WW;
    float* wT1 = wT0 + (size_t)2304 * 256;

    const int grid_t   = 2304;                       // 256*2304 weight elems / 256
    const int grid_off = BATCH * OCOFF * HH * WW / 256;   // 1944
    const int grid_df  = BATCH * HH * (WW / TP);          // 2304

    hipLaunchKernelGGL(transpose_w_kernel, dim3(grid_t), dim3(256), 0, stream, w0, wT0);
    hipLaunchKernelGGL(transpose_w_kernel, dim3(grid_t), dim3(256), 0, stream, w1, wT1);

    // Layer 0
    hipLaunchKernelGGL(offconv_kernel, dim3(grid_off), dim3(256), 0, stream, x, woff0, boff0, om);
    hipLaunchKernelGGL(dfconv_kernel,  dim3(grid_df),  dim3(256), 0, stream, x, om, wT0, h1);

    // Layer 1
    hipLaunchKernelGGL(offconv_kernel, dim3(grid_off), dim3(256), 0, stream, h1, woff1, boff1, om);
    hipLaunchKernelGGL(dfconv_kernel,  dim3(grid_df),  dim3(256), 0, stream, h1, om, wT1, out);
}

// Round 3
// 955.270 us; speedup vs baseline: 1.9154x; 1.9154x over previous
//
#include <hip/hip_runtime.h>
#include <cstdint>
#include <cstddef>

// DCNv2 x2 (B=2, C=O=256, H=W=96, k=3). Pipeline:
//   transpose x -> NHWC
//   per layer: std-im2col (bf16 hi+lo) -> split-bf16 MFMA GEMM -> om (fp32-acc)
//              def-sample (bf16)       -> bf16 MFMA GEMM (+ReLU) -> h1(NHWC)/out(NCHW)
// k reordered k' = kk*256 + c; S layout [nb][kgrp(288)][n(128)][k8(8)] bf16.

#define KTOT 2304
#define PXB  9216
#define NBLK_TOT 144
#define SPLIT 4

typedef __attribute__((ext_vector_type(8))) short bf16x8;
typedef __attribute__((ext_vector_type(4))) float f32x4;

static __device__ __forceinline__ unsigned short f2bf(float f) {
    union { float f; unsigned int u; } v; v.f = f;
    unsigned int r = (v.u + 0x7FFFu + ((v.u >> 16) & 1u)) >> 16;
    return (unsigned short)r;
}
static __device__ __forceinline__ float bf2f(unsigned short h) {
    union { unsigned int u; float f; } v; v.u = ((unsigned int)h) << 16;
    return v.f;
}

// ---------------------------------------------------------------------------
// NCHW -> NHWC transpose: in[b][c][hw] -> out[b][hw][c]
// ---------------------------------------------------------------------------
__global__ __launch_bounds__(256) void transpose_kernel(const float* __restrict__ in,
                                                        float* __restrict__ outT) {
    __shared__ float tile[64][65];
    const int hw0 = blockIdx.x * 64;
    const int c0  = blockIdx.y * 64;
    const int b   = blockIdx.z;
    const int lx  = threadIdx.x & 63;
    const int ly  = threadIdx.x >> 6;
#pragma unroll
    for (int i = 0; i < 16; ++i) {
        int cl = ly + i * 4;
        tile[cl][lx] = in[(size_t)(b * 256 + c0 + cl) * PXB + hw0 + lx];
    }
    __syncthreads();
#pragma unroll
    for (int i = 0; i < 16; ++i) {
        int hwl = ly + i * 4;
        outT[((size_t)b * PXB + hw0 + hwl) * 256 + c0 + lx] = tile[lx][hwl];
    }
}

// ---------------------------------------------------------------------------
// Main weight prep: w[o][c][kk] fp32 -> wA[o][k'=kk*256+c] bf16 (O=256 exact).
// ---------------------------------------------------------------------------
__global__ __launch_bounds__(256) void prep_w_kernel(const float* __restrict__ w,
                                                     unsigned short* __restrict__ wA) {
    int idx = blockIdx.x * 256 + threadIdx.x;   // 256*2304
    int o = idx / KTOT;
    int k = idx - o * KTOT;
    int kk = k >> 8;
    int c  = k & 255;
    wA[idx] = f2bf(w[o * KTOT + c * 9 + kk]);
}

// ---------------------------------------------------------------------------
// Offset weight prep (split): rows 27..32 zero. hi = bf16(w), lo = bf16(w-hi).
// ---------------------------------------------------------------------------
__global__ __launch_bounds__(256) void prep_woff_kernel(const float* __restrict__ w,
                                                        unsigned short* __restrict__ wH,
                                                        unsigned short* __restrict__ wL) {
    int idx = blockIdx.x * 256 + threadIdx.x;   // 32*2304
    int o = idx / KTOT;
    int k = idx - o * KTOT;
    int kk = k >> 8;
    int c  = k & 255;
    float f = (o < 27) ? w[o * KTOT + c * 9 + kk] : 0.0f;
    unsigned short hi = f2bf(f);
    wH[idx] = hi;
    wL[idx] = f2bf(f - bf2f(hi));
}

// ---------------------------------------------------------------------------
// Standard im2col sampler (NHWC input) -> S hi + lo (split bf16).
// ---------------------------------------------------------------------------
__global__ __launch_bounds__(256) void sample_std_kernel(const float* __restrict__ xt,
                                                         unsigned short* __restrict__ SH,
                                                         unsigned short* __restrict__ SL,
                                                         int nb0) {
    const int sb  = blockIdx.x;
    const int nbr = blockIdx.y;
    const int tid = threadIdx.x;
    const int n0  = (nb0 + nbr) * 128;
    const int b   = n0 / PXB;
    const int hw0 = n0 - b * PXB;

    const int kgl = sb * (288 / SPLIT);
    for (int i = 0; i < (288 / SPLIT) * 128 / 256; ++i) {   // 36 iters
        int cell = i * 256 + tid;
        int n_in = cell & 127;
        int kg   = kgl + (cell >> 7);
        int kk   = kg >> 5;
        int c0   = (kg & 31) << 3;
        int hw = hw0 + n_in;
        int h = hw / 96;
        int w = hw - h * 96;
        int y = h + (kk / 3) - 1;
        int x = w + (kk - (kk / 3) * 3) - 1;
        bool valid = ((unsigned)y < 96u) && ((unsigned)x < 96u);

        float4 v0 = make_float4(0.f, 0.f, 0.f, 0.f), v1 = v0;
        if (valid) {
            const float* p = xt + ((size_t)b * PXB + y * 96 + x) * 256 + c0;
            v0 = *(const float4*)p;
            v1 = *(const float4*)(p + 4);
        }
        float vals[8] = {v0.x, v0.y, v0.z, v0.w, v1.x, v1.y, v1.z, v1.w};
        unsigned short hi[8], lo[8];
#pragma unroll
        for (int j = 0; j < 8; ++j) {
            hi[j] = f2bf(vals[j]);
            lo[j] = f2bf(vals[j] - bf2f(hi[j]));
        }
        size_t si = ((size_t)(nbr * 288 + kg) * 128 + n_in) * 8;
        *(uint4*)&SH[si] = *(uint4*)hi;
        *(uint4*)&SL[si] = *(uint4*)lo;
    }
}

// ---------------------------------------------------------------------------
// Deformable sampler (NHWC input): geometry in LDS, 4-corner x 8-channel
// vectorized gather, mask-premultiplied -> S hi only.
// ---------------------------------------------------------------------------
__global__ __launch_bounds__(256) void sample_def_kernel(const float* __restrict__ xt,
                                                         const float* __restrict__ om,
                                                         unsigned short* __restrict__ SH,
                                                         int nb0) {
    __shared__ int   goff[1152 * 4];
    __shared__ float gwt[1152 * 4];

    const int sb  = blockIdx.x;
    const int nbr = blockIdx.y;
    const int tid = threadIdx.x;
    const int n0  = (nb0 + nbr) * 128;
    const int b   = n0 / PXB;
    const int hw0 = n0 - b * PXB;

    for (int task = tid; task < 1152; task += 256) {
        int px = task / 9;
        int kk = task - px * 9;
        int hw = hw0 + px;
        int h = hw / 96;
        int w = hw - h * 96;
        const float* omp = om + (size_t)b * 27 * PXB + hw;
        float dy = omp[(size_t)(2 * kk) * PXB];
        float dx = omp[(size_t)(2 * kk + 1) * PXB];
        float mv = omp[(size_t)(18 + kk) * PXB];
        float mk = 1.0f / (1.0f + __expf(-mv));

        float ys = (float)(h + (kk / 3) - 1) + dy;
        float xs = (float)(w + (kk - (kk / 3) * 3) - 1) + dx;
        float fy = floorf(ys), fx = floorf(xs);
        int iy = (int)fy, ix = (int)fx;
        float wy1 = ys - fy, wx1 = xs - fx;
        float wy0 = 1.0f - wy1, wx0 = 1.0f - wx1;
        bool yv0 = (unsigned)iy < 96u, yv1 = (unsigned)(iy + 1) < 96u;
        bool xv0 = (unsigned)ix < 96u, xv1 = (unsigned)(ix + 1) < 96u;
        int y0 = min(max(iy, 0), 95),     y1 = min(max(iy + 1, 0), 95);
        int x0 = min(max(ix, 0), 95),     x1 = min(max(ix + 1, 0), 95);
        int g = task * 4;
        goff[g + 0] = y0 * 96 + x0;
        goff[g + 1] = y0 * 96 + x1;
        goff[g + 2] = y1 * 96 + x0;
        goff[g + 3] = y1 * 96 + x1;
        gwt[g + 0] = (yv0 && xv0) ? mk * wy0 * wx0 : 0.0f;
        gwt[g + 1] = (yv0 && xv1) ? mk * wy0 * wx1 : 0.0f;
        gwt[g + 2] = (yv1 && xv0) ? mk * wy1 * wx0 : 0.0f;
        gwt[g + 3] = (yv1 && xv1) ? mk * wy1 * wx1 : 0.0f;
    }
    __syncthreads();

    const int kgl = sb * (288 / SPLIT);
    for (int i = 0; i < (288 / SPLIT) * 128 / 256; ++i) {   // 36 iters
        int cell = i * 256 + tid;
        int n_in = cell & 127;
        int kg   = kgl + (cell >> 7);
        int kk   = kg >> 5;
        int c0   = (kg & 31) << 3;
        int g = (n_in * 9 + kk) * 4;
        int4   off = *(int4*)&goff[g];
        float4 wt  = *(float4*)&gwt[g];
        const float* base = xt + (size_t)b * PXB * 256 + c0;

        const float* p0 = base + (size_t)off.x * 256;
        const float* p1 = base + (size_t)off.y * 256;
        const float* p2 = base + (size_t)off.z * 256;
        const float* p3 = base + (size_t)off.w * 256;
        float4 a0, a1;
        {
            float4 q0 = *(const float4*)p0, q1 = *(const float4*)p1;
            float4 q2 = *(const float4*)p2, q3 = *(const float4*)p3;
            a0.x = wt.x*q0.x + wt.y*q1.x + wt.z*q2.x + wt.w*q3.x;
            a0.y = wt.x*q0.y + wt.y*q1.y + wt.z*q2.y + wt.w*q3.y;
            a0.z = wt.x*q0.z + wt.y*q1.z + wt.z*q2.z + wt.w*q3.z;
            a0.w = wt.x*q0.w + wt.y*q1.w + wt.z*q2.w + wt.w*q3.w;
        }
        {
            float4 q0 = *(const float4*)(p0+4), q1 = *(const float4*)(p1+4);
            float4 q2 = *(const float4*)(p2+4), q3 = *(const float4*)(p3+4);
            a1.x = wt.x*q0.x + wt.y*q1.x + wt.z*q2.x + wt.w*q3.x;
            a1.y = wt.x*q0.y + wt.y*q1.y + wt.z*q2.y + wt.w*q3.y;
            a1.z = wt.x*q0.z + wt.y*q1.z + wt.z*q2.z + wt.w*q3.z;
            a1.w = wt.x*q0.w + wt.y*q1.w + wt.z*q2.w + wt.w*q3.w;
        }
        unsigned short res[8] = {f2bf(a0.x), f2bf(a0.y), f2bf(a0.z), f2bf(a0.w),
                                 f2bf(a1.x), f2bf(a1.y), f2bf(a1.z), f2bf(a1.w)};
        *(uint4*)&SH[((size_t)(nbr * 288 + kg) * 128 + n_in) * 8] = *(uint4*)res;
    }
}

// ---------------------------------------------------------------------------
// Main bf16 MFMA GEMM, 128x128 tile, BK=64, register prefetch.
// out_mode: 0 -> NCHW out[b][m][hw] ; 1 -> NHWC out[b][hw][m]. ReLU always.
// ---------------------------------------------------------------------------
__global__ __launch_bounds__(256) void gemm_kernel(const unsigned short* __restrict__ A,
                                                   const unsigned short* __restrict__ S,
                                                   float* __restrict__ out,
                                                   int nb0, int out_mode) {
    __shared__ unsigned short As[128 * 72];
    __shared__ unsigned short Bs[128 * 72];

    const int tid  = threadIdx.x;
    const int lane = tid & 63;
    const int wv   = tid >> 6;
    const int wm   = wv >> 1, wn = wv & 1;
    const int quad = lane >> 4, l16 = lane & 15;
    const int m0   = blockIdx.y * 128;
    const int nbr  = blockIdx.x;

    const int arow = tid >> 3, akg = tid & 7;
    const int bn   = tid & 31, bkg = tid >> 5;
    const unsigned short* Abase = A + (size_t)(m0 + arow) * KTOT + akg * 8;
    const unsigned short* Sbase = S + ((size_t)(nbr * 288 + bkg) * 128 + bn) * 8;

    uint4 ar[4], br[4];
#pragma unroll
    for (int r = 0; r < 4; ++r) {
        ar[r] = *(const uint4*)(Abase + (size_t)(r * 32) * KTOT);
        br[r] = *(const uint4*)(Sbase + (size_t)(r * 32) * 8);
    }

    f32x4 acc[4][4];
#pragma unroll
    for (int mt = 0; mt < 4; ++mt)
#pragma unroll
        for (int nt = 0; nt < 4; ++nt) acc[mt][nt] = (f32x4)0.0f;

    for (int kt = 0; kt < KTOT / 64; ++kt) {     // 36 iters
        __syncthreads();
#pragma unroll
        for (int r = 0; r < 4; ++r) {
            *(uint4*)&As[(arow + r * 32) * 72 + akg * 8] = ar[r];
            *(uint4*)&Bs[(bn + r * 32) * 72 + bkg * 8]   = br[r];
        }
        __syncthreads();
        if (kt + 1 < KTOT / 64) {
            const unsigned short* An = Abase + (kt + 1) * 64;
            const unsigned short* Bn = Sbase + (size_t)(kt + 1) * 8192;
#pragma unroll
            for (int r = 0; r < 4; ++r) {
                ar[r] = *(const uint4*)(An + (size_t)(r * 32) * KTOT);
                br[r] = *(const uint4*)(Bn + (size_t)(r * 32) * 8);
            }
        }
#pragma unroll
        for (int ks = 0; ks < 2; ++ks) {
            bf16x8 af[4], bfr[4];
#pragma unroll
            for (int mt = 0; mt < 4; ++mt)
                af[mt] = *(const bf16x8*)&As[(wm * 64 + mt * 16 + l16) * 72 + ks * 32 + quad * 8];
#pragma unroll
            for (int nt = 0; nt < 4; ++nt)
                bfr[nt] = *(const bf16x8*)&Bs[(wn * 64 + nt * 16 + l16) * 72 + ks * 32 + quad * 8];
#pragma unroll
            for (int mt = 0; mt < 4; ++mt)
#pragma unroll
                for (int nt = 0; nt < 4; ++nt)
                    acc[mt][nt] = __builtin_amdgcn_mfma_f32_16x16x32_bf16(
                        af[mt], bfr[nt], acc[mt][nt], 0, 0, 0);
        }
    }

    const int n0g = (nb0 + nbr) * 128;
    const int b   = n0g / PXB;
    const int hw0 = n0g - b * PXB;
#pragma unroll
    for (int mt = 0; mt < 4; ++mt) {
#pragma unroll
        for (int nt = 0; nt < 4; ++nt) {
#pragma unroll
            for (int r = 0; r < 4; ++r) {
                int m  = m0 + wm * 64 + mt * 16 + quad * 4 + r;
                int nl = wn * 64 + nt * 16 + l16;
                float v = fmaxf(acc[mt][nt][r], 0.0f);
                if (out_mode) out[((size_t)b * PXB + hw0 + nl) * 256 + m] = v;
                else          out[(size_t)(b * 256 + m) * PXB + hw0 + nl] = v;
            }
        }
    }
}

// ---------------------------------------------------------------------------
// Offset-conv GEMM: M=32 (27 real), split-bf16 3-term, fp32-accurate.
// om[b][m][hw] = relu-less, + bias.
// ---------------------------------------------------------------------------
__global__ __launch_bounds__(256) void gemm_off_kernel(const unsigned short* __restrict__ AH,
                                                       const unsigned short* __restrict__ AL,
                                                       const unsigned short* __restrict__ SH,
                                                       const unsigned short* __restrict__ SL,
                                                       const float* __restrict__ bias,
                                                       float* __restrict__ om,
                                                       int nb0) {
    __shared__ unsigned short AsH[32 * 72], AsL[32 * 72];
    __shared__ unsigned short BsH[128 * 72], BsL[128 * 72];

    const int tid  = threadIdx.x;
    const int lane = tid & 63;
    const int wv   = tid >> 6;                 // wave n-range: wv*32
    const int quad = lane >> 4, l16 = lane & 15;
    const int nbr  = blockIdx.x;

    const int arow = tid >> 3, akg = tid & 7;  // 32 rows x 8 kg
    const int bn   = tid & 31, bkg = tid >> 5;

    f32x4 acc[2][2];
#pragma unroll
    for (int mt = 0; mt < 2; ++mt)
#pragma unroll
        for (int nt = 0; nt < 2; ++nt) acc[mt][nt] = (f32x4)0.0f;

    for (int kt = 0; kt < KTOT / 64; ++kt) {
        __syncthreads();
        {
            const unsigned short* Ab = AH + (size_t)arow * KTOT + kt * 64 + akg * 8;
            const unsigned short* Al = AL + (size_t)arow * KTOT + kt * 64 + akg * 8;
            *(uint4*)&AsH[arow * 72 + akg * 8] = *(const uint4*)Ab;
            *(uint4*)&AsL[arow * 72 + akg * 8] = *(const uint4*)Al;
            const size_t sb0 = ((size_t)(nbr * 288 + kt * 8 + bkg) * 128 + bn) * 8;
#pragma unroll
            for (int r = 0; r < 4; ++r) {
                *(uint4*)&BsH[(bn + r * 32) * 72 + bkg * 8] = *(const uint4*)&SH[sb0 + (size_t)r * 32 * 8];
                *(uint4*)&BsL[(bn + r * 32) * 72 + bkg * 8] = *(const uint4*)&SL[sb0 + (size_t)r * 32 * 8];
            }
        }
        __syncthreads();
#pragma unroll
        for (int ks = 0; ks < 2; ++ks) {
            bf16x8 ah[2], al[2], bh[2], bl[2];
#pragma unroll
            for (int mt = 0; mt < 2; ++mt) {
                ah[mt] = *(const bf16x8*)&AsH[(mt * 16 + l16) * 72 + ks * 32 + quad * 8];
                al[mt] = *(const bf16x8*)&AsL[(mt * 16 + l16) * 72 + ks * 32 + quad * 8];
            }
#pragma unroll
            for (int nt = 0; nt < 2; ++nt) {
                bh[nt] = *(const bf16x8*)&BsH[(wv * 32 + nt * 16 + l16) * 72 + ks * 32 + quad * 8];
                bl[nt] = *(const bf16x8*)&BsL[(wv * 32 + nt * 16 + l16) * 72 + ks * 32 + quad * 8];
            }
#pragma unroll
            for (int mt = 0; mt < 2; ++mt)
#pragma unroll
                for (int nt = 0; nt < 2; ++nt) {
                    acc[mt][nt] = __builtin_amdgcn_mfma_f32_16x16x32_bf16(ah[mt], bh[nt], acc[mt][nt], 0, 0, 0);
                    acc[mt][nt] = __builtin_amdgcn_mfma_f32_16x16x32_bf16(ah[mt], bl[nt], acc[mt][nt], 0, 0, 0);
                    acc[mt][nt] = __builtin_amdgcn_mfma_f32_16x16x32_bf16(al[mt], bh[nt], acc[mt][nt], 0, 0, 0);
                }
        }
    }

    const int n0g = (nb0 + nbr) * 128;
    const int b   = n0g / PXB;
    const int hw0 = n0g - b * PXB;
#pragma unroll
    for (int mt = 0; mt < 2; ++mt) {
#pragma unroll
        for (int nt = 0; nt < 2; ++nt) {
#pragma unroll
            for (int r = 0; r < 4; ++r) {
                int m  = mt * 16 + quad * 4 + r;
                int nl = wv * 32 + nt * 16 + l16;
                if (m < 27)
                    om[(size_t)(b * 27 + m) * PXB + hw0 + nl] = acc[mt][nt][r] + bias[m];
            }
        }
    }
}

// ---------------------------------------------------------------------------
extern "C" void kernel_launch(void* const* d_in, const int* in_sizes, int n_in,
                              void* d_out, int out_size, void* d_ws, size_t ws_size,
                              hipStream_t stream) {
    const float* x     = (const float*)d_in[0];
    const float* woff0 = (const float*)d_in[1];
    const float* boff0 = (const float*)d_in[2];
    const float* w0    = (const float*)d_in[3];
    const float* woff1 = (const float*)d_in[4];
    const float* boff1 = (const float*)d_in[5];
    const float* w1    = (const float*)d_in[6];
    float* out = (float*)d_out;

    char* p = (char*)d_ws;
    float* om  = (float*)p;  p += (size_t)2 * 27 * PXB * 4;               // 2.0 MB
    float* xt  = (float*)p;  p += (size_t)2 * 256 * PXB * 4;              // 18.9 MB (x NHWC)
    float* h1t = (float*)p;  p += (size_t)2 * 256 * PXB * 4;              // 18.9 MB (h1 NHWC)
    unsigned short* wA0 = (unsigned short*)p; p += (size_t)256 * KTOT * 2;
    unsigned short* wA1 = (unsigned short*)p; p += (size_t)256 * KTOT * 2;
    unsigned short* wH0 = (unsigned short*)p; p += (size_t)32 * KTOT * 2;
    unsigned short* wL0 = (unsigned short*)p; p += (size_t)32 * KTOT * 2;
    unsigned short* wH1 = (unsigned short*)p; p += (size_t)32 * KTOT * 2;
    unsigned short* wL1 = (unsigned short*)p; p += (size_t)32 * KTOT * 2;
    unsigned short* SH  = (unsigned short*)p;
    size_t fixed = (size_t)(p - (char*)d_ws);

    // nblk = largest divisor of 144 such that SH+SL panels fit.
    static const int opts[] = {144, 72, 48, 36, 24, 18, 12, 9, 8, 6, 4, 3, 2, 1};
    int nblk = 1;
    for (int i = 0; i < 14; ++i) {
        if (fixed + (size_t)opts[i] * 589824 * 2 <= ws_size) { nblk = opts[i]; break; }
    }
    unsigned short* SL = SH + (size_t)nblk * 288 * 128 * 8;
    const int nchunks = NBLK_TOT / nblk;

    hipLaunchKernelGGL(transpose_kernel, dim3(PXB / 64, 4, 2), dim3(256), 0, stream, x, xt);
    hipLaunchKernelGGL(prep_w_kernel, dim3(256 * KTOT / 256), dim3(256), 0, stream, w0, wA0);
    hipLaunchKernelGGL(prep_w_kernel, dim3(256 * KTOT / 256), dim3(256), 0, stream, w1, wA1);
    hipLaunchKernelGGL(prep_woff_kernel, dim3(32 * KTOT / 256), dim3(256), 0, stream, woff0, wH0, wL0);
    hipLaunchKernelGGL(prep_woff_kernel, dim3(32 * KTOT / 256), dim3(256), 0, stream, woff1, wH1, wL1);

    for (int layer = 0; layer < 2; ++layer) {
        const float* inT = layer ? h1t : xt;
        const unsigned short* wA = layer ? wA1 : wA0;
        const unsigned short* wH = layer ? wH1 : wH0;
        const unsigned short* wL = layer ? wL1 : wL0;
        const float* bOf = layer ? boff1 : boff0;
        float* gout = layer ? out : h1t;
        int out_mode = layer ? 0 : 1;   // layer0 -> NHWC h1t, layer1 -> NCHW d_out

        for (int ci = 0; ci < nchunks; ++ci) {
            int nb0 = ci * nblk;
            hipLaunchKernelGGL(sample_std_kernel, dim3(SPLIT, nblk), dim3(256), 0, stream,
                               inT, SH, SL, nb0);
            hipLaunchKernelGGL(gemm_off_kernel, dim3(nblk), dim3(256), 0, stream,
                               wH, wL, SH, SL, bOf, om, nb0);
        }
        for (int ci = 0; ci < nchunks; ++ci) {
            int nb0 = ci * nblk;
            hipLaunchKernelGGL(sample_def_kernel, dim3(SPLIT, nblk), dim3(256), 0, stream,
                               inT, om, SH, nb0);
            hipLaunchKernelGGL(gemm_kernel, dim3(nblk, 2), dim3(256), 0, stream,
                               wA, SH, gout, nb0, out_mode);
        }
    }
}

// Round 4
// 678.603 us; speedup vs baseline: 2.6963x; 1.4077x over previous
//
#include <hip/hip_runtime.h>
#include <cstdint>
#include <cstddef>

// DCNv2 x2 (B=2, C=O=256, H=W=96, k=3), fully fused per layer:
//   offconv_fused: standard-3x3 conv via in-LDS im2col, split-bf16 3-term MFMA -> om (fp32 acc)
//   dfconv_fused : deformable sampling into LDS + bf16 MFMA GEMM (+ReLU) -> NHWC h1 / NCHW out
// k' = kk*256 + c. Activations NHWC (xt/h1t) so bilinear corners are 2x float4.

#define KTOT 2304
#define PXB  9216

typedef __attribute__((ext_vector_type(8))) short bf16x8;
typedef __attribute__((ext_vector_type(4))) float f32x4;

static __device__ __forceinline__ unsigned short f2bf(float f) {
    union { float f; unsigned int u; } v; v.f = f;
    unsigned int r = (v.u + 0x7FFFu + ((v.u >> 16) & 1u)) >> 16;
    return (unsigned short)r;
}
static __device__ __forceinline__ float bf2f(unsigned short h) {
    union { unsigned int u; float f; } v; v.u = ((unsigned int)h) << 16;
    return v.f;
}

// ---------------------------------------------------------------------------
// NCHW -> NHWC transpose
// ---------------------------------------------------------------------------
__global__ __launch_bounds__(256) void transpose_kernel(const float* __restrict__ in,
                                                        float* __restrict__ outT) {
    __shared__ float tile[64][65];
    const int hw0 = blockIdx.x * 64;
    const int c0  = blockIdx.y * 64;
    const int b   = blockIdx.z;
    const int lx  = threadIdx.x & 63;
    const int ly  = threadIdx.x >> 6;
#pragma unroll
    for (int i = 0; i < 16; ++i) {
        int cl = ly + i * 4;
        tile[cl][lx] = in[(size_t)(b * 256 + c0 + cl) * PXB + hw0 + lx];
    }
    __syncthreads();
#pragma unroll
    for (int i = 0; i < 16; ++i) {
        int hwl = ly + i * 4;
        outT[((size_t)b * PXB + hw0 + hwl) * 256 + c0 + lx] = tile[lx][hwl];
    }
}

// ---------------------------------------------------------------------------
// Main weight prep: w[o][c][kk] fp32 -> wA[o][k'=kk*256+c] bf16
// ---------------------------------------------------------------------------
__global__ __launch_bounds__(256) void prep_w_kernel(const float* __restrict__ w,
                                                     unsigned short* __restrict__ wA) {
    int idx = blockIdx.x * 256 + threadIdx.x;   // 256*2304
    int o = idx / KTOT;
    int k = idx - o * KTOT;
    int kk = k >> 8;
    int c  = k & 255;
    wA[idx] = f2bf(w[o * KTOT + c * 9 + kk]);
}

// ---------------------------------------------------------------------------
// Offset weight prep (split): rows 27..32 zero. hi = bf16(w), lo = bf16(w-hi).
// ---------------------------------------------------------------------------
__global__ __launch_bounds__(256) void prep_woff_kernel(const float* __restrict__ w,
                                                        unsigned short* __restrict__ wH,
                                                        unsigned short* __restrict__ wL) {
    int idx = blockIdx.x * 256 + threadIdx.x;   // 32*2304
    int o = idx / KTOT;
    int k = idx - o * KTOT;
    int kk = k >> 8;
    int c  = k & 255;
    float f = (o < 27) ? w[o * KTOT + c * 9 + kk] : 0.0f;
    unsigned short hi = f2bf(f);
    wH[idx] = hi;
    wL[idx] = f2bf(f - bf2f(hi));
}

// ---------------------------------------------------------------------------
// Fused offset conv: M=32(27) x N=128px x K=2304, split-bf16 3-term.
// B panel built per K-step (tap kk, 64 channels) from NHWC input in LDS.
// ---------------------------------------------------------------------------
__global__ __launch_bounds__(256) void offconv_fused(const float* __restrict__ xt,
                                                     const unsigned short* __restrict__ AH,
                                                     const unsigned short* __restrict__ AL,
                                                     const float* __restrict__ bias,
                                                     float* __restrict__ om) {
    __shared__ __attribute__((aligned(16))) unsigned short AsH[32 * 72];
    __shared__ __attribute__((aligned(16))) unsigned short AsL[32 * 72];
    __shared__ __attribute__((aligned(16))) unsigned short BsH[128 * 72];
    __shared__ __attribute__((aligned(16))) unsigned short BsL[128 * 72];

    const int tid  = threadIdx.x;
    const int lane = tid & 63, wv = tid >> 6;
    const int quad = lane >> 4, l16 = lane & 15;
    const int nb   = blockIdx.x;            // 144
    const int n0   = nb * 128;
    const int b    = n0 / PXB;
    const int hw0  = n0 - b * PXB;

    f32x4 acc[2][2];
#pragma unroll
    for (int mt = 0; mt < 2; ++mt)
#pragma unroll
        for (int nt = 0; nt < 2; ++nt) acc[mt][nt] = (f32x4)0.0f;

    const int arow = tid >> 3, akg = tid & 7;

    for (int kt = 0; kt < 36; ++kt) {
        const int kk = kt >> 2, c0 = (kt & 3) * 64;
        const int dy = kk / 3 - 1, dx = kk - (kk / 3) * 3 - 1;
        __syncthreads();
        {   // stage A (32 rows x 64 k): 1 task/thread
            size_t ai = (size_t)arow * KTOT + kt * 64 + akg * 8;
            *(uint4*)&AsH[arow * 72 + akg * 8] = *(const uint4*)&AH[ai];
            *(uint4*)&AsL[arow * 72 + akg * 8] = *(const uint4*)&AL[ai];
        }
        // stage B (128 px x 64 c): 4 tasks/thread
#pragma unroll
        for (int i = 0; i < 4; ++i) {
            int task = i * 256 + tid;
            int px = task >> 3, cg = task & 7;
            int hw = hw0 + px;
            int h = hw / 96, w = hw - h * 96;
            int y = h + dy, x = w + dx;
            bool valid = ((unsigned)y < 96u) && ((unsigned)x < 96u);
            float4 v0 = make_float4(0.f, 0.f, 0.f, 0.f), v1 = v0;
            if (valid) {
                const float* p = xt + ((size_t)b * PXB + y * 96 + x) * 256 + c0 + cg * 8;
                v0 = *(const float4*)p;
                v1 = *(const float4*)(p + 4);
            }
            float vals[8] = {v0.x, v0.y, v0.z, v0.w, v1.x, v1.y, v1.z, v1.w};
            unsigned short hi[8], lo[8];
#pragma unroll
            for (int j = 0; j < 8; ++j) {
                hi[j] = f2bf(vals[j]);
                lo[j] = f2bf(vals[j] - bf2f(hi[j]));
            }
            *(uint4*)&BsH[px * 72 + cg * 8] = *(uint4*)hi;
            *(uint4*)&BsL[px * 72 + cg * 8] = *(uint4*)lo;
        }
        __syncthreads();
#pragma unroll
        for (int ks = 0; ks < 2; ++ks) {
            bf16x8 ah[2], al[2], bh[2], bl[2];
#pragma unroll
            for (int mt = 0; mt < 2; ++mt) {
                ah[mt] = *(const bf16x8*)&AsH[(mt * 16 + l16) * 72 + ks * 32 + quad * 8];
                al[mt] = *(const bf16x8*)&AsL[(mt * 16 + l16) * 72 + ks * 32 + quad * 8];
            }
#pragma unroll
            for (int nt = 0; nt < 2; ++nt) {
                bh[nt] = *(const bf16x8*)&BsH[(wv * 32 + nt * 16 + l16) * 72 + ks * 32 + quad * 8];
                bl[nt] = *(const bf16x8*)&BsL[(wv * 32 + nt * 16 + l16) * 72 + ks * 32 + quad * 8];
            }
#pragma unroll
            for (int mt = 0; mt < 2; ++mt)
#pragma unroll
                for (int nt = 0; nt < 2; ++nt) {
                    acc[mt][nt] = __builtin_amdgcn_mfma_f32_16x16x32_bf16(ah[mt], bh[nt], acc[mt][nt], 0, 0, 0);
                    acc[mt][nt] = __builtin_amdgcn_mfma_f32_16x16x32_bf16(ah[mt], bl[nt], acc[mt][nt], 0, 0, 0);
                    acc[mt][nt] = __builtin_amdgcn_mfma_f32_16x16x32_bf16(al[mt], bh[nt], acc[mt][nt], 0, 0, 0);
                }
        }
    }

#pragma unroll
    for (int mt = 0; mt < 2; ++mt)
#pragma unroll
        for (int nt = 0; nt < 2; ++nt)
#pragma unroll
            for (int r = 0; r < 4; ++r) {
                int m = mt * 16 + quad * 4 + r;
                int n = wv * 32 + nt * 16 + l16;
                if (m < 27)
                    om[(size_t)(b * 27 + m) * PXB + hw0 + n] = acc[mt][nt][r] + bias[m];
            }
}

// ---------------------------------------------------------------------------
// Fused deformable conv: tile 128m x 64n, full K=2304. Grid (288, 2).
// Geometry once/block into LDS; B gathered per K-step; A register-prefetched.
// out_mode: 0 -> NCHW direct stores; 1 -> NHWC via LDS-staged epilogue.
// ---------------------------------------------------------------------------
__global__ __launch_bounds__(256) void dfconv_fused(const float* __restrict__ xt,
                                                    const float* __restrict__ om,
                                                    const unsigned short* __restrict__ A,
                                                    float* __restrict__ out,
                                                    int out_mode) {
    __shared__ __attribute__((aligned(16))) unsigned short As[128 * 72];
    __shared__ __attribute__((aligned(16))) unsigned short Bs[64 * 72];
    __shared__ __attribute__((aligned(16))) unsigned short goff[576 * 4];
    __shared__ __attribute__((aligned(16))) float gwt[576 * 4];

    const int tid  = threadIdx.x;
    const int lane = tid & 63, wv = tid >> 6;
    const int quad = lane >> 4, l16 = lane & 15;
    const int wn   = wv & 1, wm = wv >> 1;
    const int nb   = blockIdx.x;            // 288 (64 px each)
    const int m0   = blockIdx.y * 128;
    const int n0   = nb * 64;
    const int b    = n0 / PXB;
    const int hw0  = n0 - b * PXB;

    // ---- geometry: 64 px x 9 taps ----
    for (int task = tid; task < 576; task += 256) {
        int px = task / 9;
        int kk = task - px * 9;
        int hw = hw0 + px;
        int h = hw / 96, w = hw - h * 96;
        const float* omp = om + (size_t)b * 27 * PXB + hw;
        float dy = omp[(size_t)(2 * kk) * PXB];
        float dx = omp[(size_t)(2 * kk + 1) * PXB];
        float mv = omp[(size_t)(18 + kk) * PXB];
        float mk = 1.0f / (1.0f + __expf(-mv));

        float ys = (float)(h + (kk / 3) - 1) + dy;
        float xs = (float)(w + (kk - (kk / 3) * 3) - 1) + dx;
        float fy = floorf(ys), fx = floorf(xs);
        int iy = (int)fy, ix = (int)fx;
        float wy1 = ys - fy, wx1 = xs - fx;
        float wy0 = 1.0f - wy1, wx0 = 1.0f - wx1;
        bool yv0 = (unsigned)iy < 96u, yv1 = (unsigned)(iy + 1) < 96u;
        bool xv0 = (unsigned)ix < 96u, xv1 = (unsigned)(ix + 1) < 96u;
        int y0 = min(max(iy, 0), 95),     y1 = min(max(iy + 1, 0), 95);
        int x0 = min(max(ix, 0), 95),     x1 = min(max(ix + 1, 0), 95);
        int g = task * 4;
        goff[g + 0] = (unsigned short)(y0 * 96 + x0);
        goff[g + 1] = (unsigned short)(y0 * 96 + x1);
        goff[g + 2] = (unsigned short)(y1 * 96 + x0);
        goff[g + 3] = (unsigned short)(y1 * 96 + x1);
        gwt[g + 0] = (yv0 && xv0) ? mk * wy0 * wx0 : 0.0f;
        gwt[g + 1] = (yv0 && xv1) ? mk * wy0 * wx1 : 0.0f;
        gwt[g + 2] = (yv1 && xv0) ? mk * wy1 * wx0 : 0.0f;
        gwt[g + 3] = (yv1 && xv1) ? mk * wy1 * wx1 : 0.0f;
    }

    // ---- A prefetch (kt=0) ----
    const int arow = tid >> 3, akg = tid & 7;
    const unsigned short* Abase = A + (size_t)(m0 + arow) * KTOT + akg * 8;
    uint4 ar[4];
#pragma unroll
    for (int r = 0; r < 4; ++r)
        ar[r] = *(const uint4*)(Abase + (size_t)(r * 32) * KTOT);

    f32x4 acc[4][2];
#pragma unroll
    for (int mt = 0; mt < 4; ++mt)
#pragma unroll
        for (int nt = 0; nt < 2; ++nt) acc[mt][nt] = (f32x4)0.0f;

    __syncthreads();   // geometry ready

    const float* xbase = xt + (size_t)b * PXB * 256;

    for (int kt = 0; kt < 36; ++kt) {
        const int kk = kt >> 2, c0 = (kt & 3) * 64;
        // write A regs to LDS
#pragma unroll
        for (int r = 0; r < 4; ++r)
            *(uint4*)&As[(arow + r * 32) * 72 + akg * 8] = ar[r];
        // sample B (64 px x 64 c): 2 tasks/thread
#pragma unroll
        for (int i = 0; i < 2; ++i) {
            int task = i * 256 + tid;
            int px = task >> 3, cg = task & 7;
            int g = (px * 9 + kk) * 4;
            ushort4 off4 = *(const ushort4*)&goff[g];
            float4  wt   = *(const float4*)&gwt[g];
            const float* cb = xbase + c0 + cg * 8;
            const float* p0 = cb + (size_t)off4.x * 256;
            const float* p1 = cb + (size_t)off4.y * 256;
            const float* p2 = cb + (size_t)off4.z * 256;
            const float* p3 = cb + (size_t)off4.w * 256;
            float4 q0 = *(const float4*)p0, q1 = *(const float4*)p1;
            float4 q2 = *(const float4*)p2, q3 = *(const float4*)p3;
            float4 r0 = *(const float4*)(p0 + 4), r1 = *(const float4*)(p1 + 4);
            float4 r2 = *(const float4*)(p2 + 4), r3 = *(const float4*)(p3 + 4);
            unsigned short res[8];
            res[0] = f2bf(wt.x*q0.x + wt.y*q1.x + wt.z*q2.x + wt.w*q3.x);
            res[1] = f2bf(wt.x*q0.y + wt.y*q1.y + wt.z*q2.y + wt.w*q3.y);
            res[2] = f2bf(wt.x*q0.z + wt.y*q1.z + wt.z*q2.z + wt.w*q3.z);
            res[3] = f2bf(wt.x*q0.w + wt.y*q1.w + wt.z*q2.w + wt.w*q3.w);
            res[4] = f2bf(wt.x*r0.x + wt.y*r1.x + wt.z*r2.x + wt.w*r3.x);
            res[5] = f2bf(wt.x*r0.y + wt.y*r1.y + wt.z*r2.y + wt.w*r3.y);
            res[6] = f2bf(wt.x*r0.z + wt.y*r1.z + wt.z*r2.z + wt.w*r3.z);
            res[7] = f2bf(wt.x*r0.w + wt.y*r1.w + wt.z*r2.w + wt.w*r3.w);
            *(uint4*)&Bs[px * 72 + cg * 8] = *(uint4*)res;
        }
        __syncthreads();
        // prefetch next A chunk
        if (kt + 1 < 36) {
#pragma unroll
            for (int r = 0; r < 4; ++r)
                ar[r] = *(const uint4*)(Abase + (kt + 1) * 64 + (size_t)(r * 32) * KTOT);
        }
        // MFMA
#pragma unroll
        for (int ks = 0; ks < 2; ++ks) {
            bf16x8 af[4], bfr[2];
#pragma unroll
            for (int mt = 0; mt < 4; ++mt)
                af[mt] = *(const bf16x8*)&As[(wm * 64 + mt * 16 + l16) * 72 + ks * 32 + quad * 8];
#pragma unroll
            for (int nt = 0; nt < 2; ++nt)
                bfr[nt] = *(const bf16x8*)&Bs[(wn * 32 + nt * 16 + l16) * 72 + ks * 32 + quad * 8];
#pragma unroll
            for (int mt = 0; mt < 4; ++mt)
#pragma unroll
                for (int nt = 0; nt < 2; ++nt)
                    acc[mt][nt] = __builtin_amdgcn_mfma_f32_16x16x32_bf16(
                        af[mt], bfr[nt], acc[mt][nt], 0, 0, 0);
        }
        __syncthreads();
    }

    if (out_mode == 0) {
        // NCHW: out[b][m][hw] — lanes along hw, 64B-dense
#pragma unroll
        for (int mt = 0; mt < 4; ++mt)
#pragma unroll
            for (int nt = 0; nt < 2; ++nt)
#pragma unroll
                for (int r = 0; r < 4; ++r) {
                    int m = m0 + wm * 64 + mt * 16 + quad * 4 + r;
                    int n = wn * 32 + nt * 16 + l16;
                    out[(size_t)(b * 256 + m) * PXB + hw0 + n] = fmaxf(acc[mt][nt][r], 0.0f);
                }
    } else {
        // NHWC via LDS staging: two passes of 32 px, 512B-dense stores
        float* tileF = (float*)As;    // 32 x 132 floats = 16.9 KB (fits in As)
#pragma unroll
        for (int pass = 0; pass < 2; ++pass) {
            __syncthreads();
            if (wn == pass) {
#pragma unroll
                for (int mt = 0; mt < 4; ++mt)
#pragma unroll
                    for (int nt = 0; nt < 2; ++nt) {
                        int row = nt * 16 + l16;
                        int col = wm * 64 + mt * 16 + quad * 4;
                        f32x4 v = acc[mt][nt];
                        v[0] = fmaxf(v[0], 0.f); v[1] = fmaxf(v[1], 0.f);
                        v[2] = fmaxf(v[2], 0.f); v[3] = fmaxf(v[3], 0.f);
                        *(f32x4*)&tileF[row * 132 + col] = v;
                    }
            }
            __syncthreads();
            int px = tid >> 3, mc = (tid & 7) * 16;
            float* op = out + ((size_t)b * PXB + hw0 + pass * 32 + px) * 256 + m0 + mc;
            const float* tp = &tileF[px * 132 + mc];
#pragma unroll
            for (int j = 0; j < 4; ++j)
                *(float4*)(op + j * 4) = *(const float4*)(tp + j * 4);
        }
    }
}

// ---------------------------------------------------------------------------
extern "C" void kernel_launch(void* const* d_in, const int* in_sizes, int n_in,
                              void* d_out, int out_size, void* d_ws, size_t ws_size,
                              hipStream_t stream) {
    const float* x     = (const float*)d_in[0];
    const float* woff0 = (const float*)d_in[1];
    const float* boff0 = (const float*)d_in[2];
    const float* w0    = (const float*)d_in[3];
    const float* woff1 = (const float*)d_in[4];
    const float* boff1 = (const float*)d_in[5];
    const float* w1    = (const float*)d_in[6];
    float* out = (float*)d_out;

    char* p = (char*)d_ws;
    float* om  = (float*)p;  p += (size_t)2 * 27 * PXB * 4;               // 2.0 MB
    float* xt  = (float*)p;  p += (size_t)2 * 256 * PXB * 4;              // 18.9 MB
    float* h1t = (float*)p;  p += (size_t)2 * 256 * PXB * 4;              // 18.9 MB
    unsigned short* wA0 = (unsigned short*)p; p += (size_t)256 * KTOT * 2;
    unsigned short* wA1 = (unsigned short*)p; p += (size_t)256 * KTOT * 2;
    unsigned short* wH0 = (unsigned short*)p; p += (size_t)32 * KTOT * 2;
    unsigned short* wL0 = (unsigned short*)p; p += (size_t)32 * KTOT * 2;
    unsigned short* wH1 = (unsigned short*)p; p += (size_t)32 * KTOT * 2;
    unsigned short* wL1 = (unsigned short*)p; p += (size_t)32 * KTOT * 2;

    hipLaunchKernelGGL(transpose_kernel, dim3(PXB / 64, 4, 2), dim3(256), 0, stream, x, xt);
    hipLaunchKernelGGL(prep_w_kernel, dim3(256 * KTOT / 256), dim3(256), 0, stream, w0, wA0);
    hipLaunchKernelGGL(prep_w_kernel, dim3(256 * KTOT / 256), dim3(256), 0, stream, w1, wA1);
    hipLaunchKernelGGL(prep_woff_kernel, dim3(32 * KTOT / 256), dim3(256), 0, stream, woff0, wH0, wL0);
    hipLaunchKernelGGL(prep_woff_kernel, dim3(32 * KTOT / 256), dim3(256), 0, stream, woff1, wH1, wL1);

    // Layer 0: x(NHWC) -> h1t(NHWC)
    hipLaunchKernelGGL(offconv_fused, dim3(144), dim3(256), 0, stream, xt, wH0, wL0, boff0, om);
    hipLaunchKernelGGL(dfconv_fused, dim3(288, 2), dim3(256), 0, stream, xt, om, wA0, h1t, 1);

    // Layer 1: h1t(NHWC) -> out(NCHW)
    hipLaunchKernelGGL(offconv_fused, dim3(144), dim3(256), 0, stream, h1t, wH1, wL1, boff1, om);
    hipLaunchKernelGGL(dfconv_fused, dim3(288, 2), dim3(256), 0, stream, h1t, om, wA1, out, 0);
}

// Round 5
// 549.140 us; speedup vs baseline: 3.3320x; 1.2358x over previous
//
#include <hip/hip_runtime.h>
#include <cstdint>
#include <cstddef>

// DCNv2 x2 (B=2, C=O=256, H=W=96, k=3), fully fused per layer:
//   offconv_fused: standard-3x3 conv via in-LDS im2col, split-bf16 3-term MFMA -> om (fp32 acc)
//   dfconv_fused : deformable sampling into LDS + bf16 MFMA GEMM (+ReLU) -> NHWC h1 / NCHW out
// k' = kk*256 + c. Activations NHWC (xt/h1t) so bilinear corners are 2x float4.
// XCD swizzle: blockIdx % 8 = XCD (round-robin dispatch); renumber so each XCD
// works a contiguous 1/8-image slice (2.25 MB) -> gather + A stay L2-resident.

#define KTOT 2304
#define PXB  9216

typedef __attribute__((ext_vector_type(8))) short bf16x8;
typedef __attribute__((ext_vector_type(4))) float f32x4;

static __device__ __forceinline__ unsigned short f2bf(float f) {
    union { float f; unsigned int u; } v; v.f = f;
    unsigned int r = (v.u + 0x7FFFu + ((v.u >> 16) & 1u)) >> 16;
    return (unsigned short)r;
}
static __device__ __forceinline__ float bf2f(unsigned short h) {
    union { unsigned int u; float f; } v; v.u = ((unsigned int)h) << 16;
    return v.f;
}

// ---------------------------------------------------------------------------
// NCHW -> NHWC transpose
// ---------------------------------------------------------------------------
__global__ __launch_bounds__(256) void transpose_kernel(const float* __restrict__ in,
                                                        float* __restrict__ outT) {
    __shared__ float tile[64][65];
    const int hw0 = blockIdx.x * 64;
    const int c0  = blockIdx.y * 64;
    const int b   = blockIdx.z;
    const int lx  = threadIdx.x & 63;
    const int ly  = threadIdx.x >> 6;
#pragma unroll
    for (int i = 0; i < 16; ++i) {
        int cl = ly + i * 4;
        tile[cl][lx] = in[(size_t)(b * 256 + c0 + cl) * PXB + hw0 + lx];
    }
    __syncthreads();
#pragma unroll
    for (int i = 0; i < 16; ++i) {
        int hwl = ly + i * 4;
        outT[((size_t)b * PXB + hw0 + hwl) * 256 + c0 + lx] = tile[lx][hwl];
    }
}

// ---------------------------------------------------------------------------
// Main weight prep: w[o][c][kk] fp32 -> wA[o][k'=kk*256+c] bf16
// ---------------------------------------------------------------------------
__global__ __launch_bounds__(256) void prep_w_kernel(const float* __restrict__ w,
                                                     unsigned short* __restrict__ wA) {
    int idx = blockIdx.x * 256 + threadIdx.x;   // 256*2304
    int o = idx / KTOT;
    int k = idx - o * KTOT;
    int kk = k >> 8;
    int c  = k & 255;
    wA[idx] = f2bf(w[o * KTOT + c * 9 + kk]);
}

// ---------------------------------------------------------------------------
// Offset weight prep (split): rows 27..32 zero. hi = bf16(w), lo = bf16(w-hi).
// ---------------------------------------------------------------------------
__global__ __launch_bounds__(256) void prep_woff_kernel(const float* __restrict__ w,
                                                        unsigned short* __restrict__ wH,
                                                        unsigned short* __restrict__ wL) {
    int idx = blockIdx.x * 256 + threadIdx.x;   // 32*2304
    int o = idx / KTOT;
    int k = idx - o * KTOT;
    int kk = k >> 8;
    int c  = k & 255;
    float f = (o < 27) ? w[o * KTOT + c * 9 + kk] : 0.0f;
    unsigned short hi = f2bf(f);
    wH[idx] = hi;
    wL[idx] = f2bf(f - bf2f(hi));
}

// ---------------------------------------------------------------------------
// Fused offset conv: M=32(27) x N=64px x K=2304, split-bf16 3-term.
// Grid 288, XCD-swizzled. B panel built per K-step in LDS.
// ---------------------------------------------------------------------------
__global__ __launch_bounds__(256) void offconv_fused(const float* __restrict__ xt,
                                                     const unsigned short* __restrict__ AH,
                                                     const unsigned short* __restrict__ AL,
                                                     const float* __restrict__ bias,
                                                     float* __restrict__ om) {
    __shared__ __attribute__((aligned(16))) unsigned short AsH[32 * 72];
    __shared__ __attribute__((aligned(16))) unsigned short AsL[32 * 72];
    __shared__ __attribute__((aligned(16))) unsigned short BsH[64 * 72];
    __shared__ __attribute__((aligned(16))) unsigned short BsL[64 * 72];

    const int tid  = threadIdx.x;
    const int lane = tid & 63, wv = tid >> 6;
    const int quad = lane >> 4, l16 = lane & 15;
    // XCD swizzle: xcd = g%8 owns n-blocks [xcd*36, xcd*36+36)
    const int g    = blockIdx.x;            // 288
    const int nb   = (g & 7) * 36 + (g >> 3);
    const int n0   = nb * 64;
    const int b    = n0 / PXB;
    const int hw0  = n0 - b * PXB;

    f32x4 acc[2];
#pragma unroll
    for (int mt = 0; mt < 2; ++mt) acc[mt] = (f32x4)0.0f;

    const int arow = tid >> 3, akg = tid & 7;

    for (int kt = 0; kt < 36; ++kt) {
        const int kk = kt >> 2, c0 = (kt & 3) * 64;
        const int dy = kk / 3 - 1, dx = kk - (kk / 3) * 3 - 1;
        __syncthreads();
        {   // stage A (32 rows x 64 k)
            size_t ai = (size_t)arow * KTOT + kt * 64 + akg * 8;
            *(uint4*)&AsH[arow * 72 + akg * 8] = *(const uint4*)&AH[ai];
            *(uint4*)&AsL[arow * 72 + akg * 8] = *(const uint4*)&AL[ai];
        }
        // stage B (64 px x 64 c): 2 tasks/thread
#pragma unroll
        for (int i = 0; i < 2; ++i) {
            int task = i * 256 + tid;
            int px = task >> 3, cg = task & 7;
            int hw = hw0 + px;
            int h = hw / 96, w = hw - h * 96;
            int y = h + dy, x = w + dx;
            bool valid = ((unsigned)y < 96u) && ((unsigned)x < 96u);
            float4 v0 = make_float4(0.f, 0.f, 0.f, 0.f), v1 = v0;
            if (valid) {
                const float* p = xt + ((size_t)b * PXB + y * 96 + x) * 256 + c0 + cg * 8;
                v0 = *(const float4*)p;
                v1 = *(const float4*)(p + 4);
            }
            float vals[8] = {v0.x, v0.y, v0.z, v0.w, v1.x, v1.y, v1.z, v1.w};
            unsigned short hi[8], lo[8];
#pragma unroll
            for (int j = 0; j < 8; ++j) {
                hi[j] = f2bf(vals[j]);
                lo[j] = f2bf(vals[j] - bf2f(hi[j]));
            }
            *(uint4*)&BsH[px * 72 + cg * 8] = *(uint4*)hi;
            *(uint4*)&BsL[px * 72 + cg * 8] = *(uint4*)lo;
        }
        __syncthreads();
#pragma unroll
        for (int ks = 0; ks < 2; ++ks) {
            bf16x8 ah[2], al[2], bh, bl;
#pragma unroll
            for (int mt = 0; mt < 2; ++mt) {
                ah[mt] = *(const bf16x8*)&AsH[(mt * 16 + l16) * 72 + ks * 32 + quad * 8];
                al[mt] = *(const bf16x8*)&AsL[(mt * 16 + l16) * 72 + ks * 32 + quad * 8];
            }
            bh = *(const bf16x8*)&BsH[(wv * 16 + l16) * 72 + ks * 32 + quad * 8];
            bl = *(const bf16x8*)&BsL[(wv * 16 + l16) * 72 + ks * 32 + quad * 8];
#pragma unroll
            for (int mt = 0; mt < 2; ++mt) {
                acc[mt] = __builtin_amdgcn_mfma_f32_16x16x32_bf16(ah[mt], bh, acc[mt], 0, 0, 0);
                acc[mt] = __builtin_amdgcn_mfma_f32_16x16x32_bf16(ah[mt], bl, acc[mt], 0, 0, 0);
                acc[mt] = __builtin_amdgcn_mfma_f32_16x16x32_bf16(al[mt], bh, acc[mt], 0, 0, 0);
            }
        }
    }

#pragma unroll
    for (int mt = 0; mt < 2; ++mt)
#pragma unroll
        for (int r = 0; r < 4; ++r) {
            int m = mt * 16 + quad * 4 + r;
            int n = wv * 16 + l16;
            if (m < 27)
                om[(size_t)(b * 27 + m) * PXB + hw0 + n] = acc[mt][r] + bias[m];
        }
}

// ---------------------------------------------------------------------------
// Fused deformable conv: tile 128m x 64n, full K=2304. Grid 576 (XCD-swizzled:
// each XCD gets 36 consecutive n-blocks x both m-halves, halves adjacent).
// out_mode: 0 -> NCHW direct stores; 1 -> NHWC via LDS-staged epilogue.
// ---------------------------------------------------------------------------
__global__ __launch_bounds__(256) void dfconv_fused(const float* __restrict__ xt,
                                                    const float* __restrict__ om,
                                                    const unsigned short* __restrict__ A,
                                                    float* __restrict__ out,
                                                    int out_mode) {
    __shared__ __attribute__((aligned(16))) unsigned short As[128 * 72];
    __shared__ __attribute__((aligned(16))) unsigned short Bs[64 * 72];
    __shared__ __attribute__((aligned(16))) unsigned short goff[576 * 4];
    __shared__ __attribute__((aligned(16))) float gwt[576 * 4];

    const int tid  = threadIdx.x;
    const int lane = tid & 63, wv = tid >> 6;
    const int quad = lane >> 4, l16 = lane & 15;
    const int wn   = wv & 1, wm = wv >> 1;
    // XCD swizzle: g%8 = xcd; s = g/8; nb = xcd*36 + s/2; my = s%2.
    const int g    = blockIdx.x;            // 576
    const int s    = g >> 3;
    const int nb   = (g & 7) * 36 + (s >> 1);
    const int m0   = (s & 1) * 128;
    const int n0   = nb * 64;
    const int b    = n0 / PXB;
    const int hw0  = n0 - b * PXB;

    // ---- geometry: 64 px x 9 taps ----
    for (int task = tid; task < 576; task += 256) {
        int px = task / 9;
        int kk = task - px * 9;
        int hw = hw0 + px;
        int h = hw / 96, w = hw - h * 96;
        const float* omp = om + (size_t)b * 27 * PXB + hw;
        float dy = omp[(size_t)(2 * kk) * PXB];
        float dx = omp[(size_t)(2 * kk + 1) * PXB];
        float mv = omp[(size_t)(18 + kk) * PXB];
        float mk = 1.0f / (1.0f + __expf(-mv));

        float ys = (float)(h + (kk / 3) - 1) + dy;
        float xs = (float)(w + (kk - (kk / 3) * 3) - 1) + dx;
        float fy = floorf(ys), fx = floorf(xs);
        int iy = (int)fy, ix = (int)fx;
        float wy1 = ys - fy, wx1 = xs - fx;
        float wy0 = 1.0f - wy1, wx0 = 1.0f - wx1;
        bool yv0 = (unsigned)iy < 96u, yv1 = (unsigned)(iy + 1) < 96u;
        bool xv0 = (unsigned)ix < 96u, xv1 = (unsigned)(ix + 1) < 96u;
        int y0 = min(max(iy, 0), 95),     y1 = min(max(iy + 1, 0), 95);
        int x0 = min(max(ix, 0), 95),     x1 = min(max(ix + 1, 0), 95);
        int gg = task * 4;
        goff[gg + 0] = (unsigned short)(y0 * 96 + x0);
        goff[gg + 1] = (unsigned short)(y0 * 96 + x1);
        goff[gg + 2] = (unsigned short)(y1 * 96 + x0);
        goff[gg + 3] = (unsigned short)(y1 * 96 + x1);
        gwt[gg + 0] = (yv0 && xv0) ? mk * wy0 * wx0 : 0.0f;
        gwt[gg + 1] = (yv0 && xv1) ? mk * wy0 * wx1 : 0.0f;
        gwt[gg + 2] = (yv1 && xv0) ? mk * wy1 * wx0 : 0.0f;
        gwt[gg + 3] = (yv1 && xv1) ? mk * wy1 * wx1 : 0.0f;
    }

    // ---- A prefetch (kt=0) ----
    const int arow = tid >> 3, akg = tid & 7;
    const unsigned short* Abase = A + (size_t)(m0 + arow) * KTOT + akg * 8;
    uint4 ar[4];
#pragma unroll
    for (int r = 0; r < 4; ++r)
        ar[r] = *(const uint4*)(Abase + (size_t)(r * 32) * KTOT);

    f32x4 acc[4][2];
#pragma unroll
    for (int mt = 0; mt < 4; ++mt)
#pragma unroll
        for (int nt = 0; nt < 2; ++nt) acc[mt][nt] = (f32x4)0.0f;

    __syncthreads();   // geometry ready

    const float* xbase = xt + (size_t)b * PXB * 256;

    for (int kt = 0; kt < 36; ++kt) {
        const int kk = kt >> 2, c0 = (kt & 3) * 64;
        // write A regs to LDS
#pragma unroll
        for (int r = 0; r < 4; ++r)
            *(uint4*)&As[(arow + r * 32) * 72 + akg * 8] = ar[r];
        // sample B (64 px x 64 c): 2 tasks/thread
#pragma unroll
        for (int i = 0; i < 2; ++i) {
            int task = i * 256 + tid;
            int px = task >> 3, cg = task & 7;
            int gg = (px * 9 + kk) * 4;
            ushort4 off4 = *(const ushort4*)&goff[gg];
            float4  wt   = *(const float4*)&gwt[gg];
            const float* cb = xbase + c0 + cg * 8;
            const float* p0 = cb + (size_t)off4.x * 256;
            const float* p1 = cb + (size_t)off4.y * 256;
            const float* p2 = cb + (size_t)off4.z * 256;
            const float* p3 = cb + (size_t)off4.w * 256;
            float4 q0 = *(const float4*)p0, q1 = *(const float4*)p1;
            float4 q2 = *(const float4*)p2, q3 = *(const float4*)p3;
            float4 r0 = *(const float4*)(p0 + 4), r1 = *(const float4*)(p1 + 4);
            float4 r2 = *(const float4*)(p2 + 4), r3 = *(const float4*)(p3 + 4);
            unsigned short res[8];
            res[0] = f2bf(wt.x*q0.x + wt.y*q1.x + wt.z*q2.x + wt.w*q3.x);
            res[1] = f2bf(wt.x*q0.y + wt.y*q1.y + wt.z*q2.y + wt.w*q3.y);
            res[2] = f2bf(wt.x*q0.z + wt.y*q1.z + wt.z*q2.z + wt.w*q3.z);
            res[3] = f2bf(wt.x*q0.w + wt.y*q1.w + wt.z*q2.w + wt.w*q3.w);
            res[4] = f2bf(wt.x*r0.x + wt.y*r1.x + wt.z*r2.x + wt.w*r3.x);
            res[5] = f2bf(wt.x*r0.y + wt.y*r1.y + wt.z*r2.y + wt.w*r3.y);
            res[6] = f2bf(wt.x*r0.z + wt.y*r1.z + wt.z*r2.z + wt.w*r3.z);
            res[7] = f2bf(wt.x*r0.w + wt.y*r1.w + wt.z*r2.w + wt.w*r3.w);
            *(uint4*)&Bs[px * 72 + cg * 8] = *(uint4*)res;
        }
        __syncthreads();
        // prefetch next A chunk
        if (kt + 1 < 36) {
#pragma unroll
            for (int r = 0; r < 4; ++r)
                ar[r] = *(const uint4*)(Abase + (kt + 1) * 64 + (size_t)(r * 32) * KTOT);
        }
        // MFMA
#pragma unroll
        for (int ks = 0; ks < 2; ++ks) {
            bf16x8 af[4], bfr[2];
#pragma unroll
            for (int mt = 0; mt < 4; ++mt)
                af[mt] = *(const bf16x8*)&As[(wm * 64 + mt * 16 + l16) * 72 + ks * 32 + quad * 8];
#pragma unroll
            for (int nt = 0; nt < 2; ++nt)
                bfr[nt] = *(const bf16x8*)&Bs[(wn * 32 + nt * 16 + l16) * 72 + ks * 32 + quad * 8];
#pragma unroll
            for (int mt = 0; mt < 4; ++mt)
#pragma unroll
                for (int nt = 0; nt < 2; ++nt)
                    acc[mt][nt] = __builtin_amdgcn_mfma_f32_16x16x32_bf16(
                        af[mt], bfr[nt], acc[mt][nt], 0, 0, 0);
        }
        __syncthreads();
    }

    if (out_mode == 0) {
        // NCHW: out[b][m][hw] — lanes along hw, 64B-dense
#pragma unroll
        for (int mt = 0; mt < 4; ++mt)
#pragma unroll
            for (int nt = 0; nt < 2; ++nt)
#pragma unroll
                for (int r = 0; r < 4; ++r) {
                    int m = m0 + wm * 64 + mt * 16 + quad * 4 + r;
                    int n = wn * 32 + nt * 16 + l16;
                    out[(size_t)(b * 256 + m) * PXB + hw0 + n] = fmaxf(acc[mt][nt][r], 0.0f);
                }
    } else {
        // NHWC via LDS staging: two passes of 32 px, 512B-dense stores
        float* tileF = (float*)As;    // 32 x 132 floats = 16.9 KB (fits in As)
#pragma unroll
        for (int pass = 0; pass < 2; ++pass) {
            __syncthreads();
            if (wn == pass) {
#pragma unroll
                for (int mt = 0; mt < 4; ++mt)
#pragma unroll
                    for (int nt = 0; nt < 2; ++nt) {
                        int row = nt * 16 + l16;
                        int col = wm * 64 + mt * 16 + quad * 4;
                        f32x4 v = acc[mt][nt];
                        v[0] = fmaxf(v[0], 0.f); v[1] = fmaxf(v[1], 0.f);
                        v[2] = fmaxf(v[2], 0.f); v[3] = fmaxf(v[3], 0.f);
                        *(f32x4*)&tileF[row * 132 + col] = v;
                    }
            }
            __syncthreads();
            int px = tid >> 3, mc = (tid & 7) * 16;
            float* op = out + ((size_t)b * PXB + hw0 + pass * 32 + px) * 256 + m0 + mc;
            const float* tp = &tileF[px * 132 + mc];
#pragma unroll
            for (int j = 0; j < 4; ++j)
                *(float4*)(op + j * 4) = *(const float4*)(tp + j * 4);
        }
    }
}

// ---------------------------------------------------------------------------
extern "C" void kernel_launch(void* const* d_in, const int* in_sizes, int n_in,
                              void* d_out, int out_size, void* d_ws, size_t ws_size,
                              hipStream_t stream) {
    const float* x     = (const float*)d_in[0];
    const float* woff0 = (const float*)d_in[1];
    const float* boff0 = (const float*)d_in[2];
    const float* w0    = (const float*)d_in[3];
    const float* woff1 = (const float*)d_in[4];
    const float* boff1 = (const float*)d_in[5];
    const float* w1    = (const float*)d_in[6];
    float* out = (float*)d_out;

    char* p = (char*)d_ws;
    float* om  = (float*)p;  p += (size_t)2 * 27 * PXB * 4;               // 2.0 MB
    float* xt  = (float*)p;  p += (size_t)2 * 256 * PXB * 4;              // 18.9 MB
    float* h1t = (float*)p;  p += (size_t)2 * 256 * PXB * 4;              // 18.9 MB
    unsigned short* wA0 = (unsigned short*)p; p += (size_t)256 * KTOT * 2;
    unsigned short* wA1 = (unsigned short*)p; p += (size_t)256 * KTOT * 2;
    unsigned short* wH0 = (unsigned short*)p; p += (size_t)32 * KTOT * 2;
    unsigned short* wL0 = (unsigned short*)p; p += (size_t)32 * KTOT * 2;
    unsigned short* wH1 = (unsigned short*)p; p += (size_t)32 * KTOT * 2;
    unsigned short* wL1 = (unsigned short*)p; p += (size_t)32 * KTOT * 2;

    hipLaunchKernelGGL(transpose_kernel, dim3(PXB / 64, 4, 2), dim3(256), 0, stream, x, xt);
    hipLaunchKernelGGL(prep_w_kernel, dim3(256 * KTOT / 256), dim3(256), 0, stream, w0, wA0);
    hipLaunchKernelGGL(prep_w_kernel, dim3(256 * KTOT / 256), dim3(256), 0, stream, w1, wA1);
    hipLaunchKernelGGL(prep_woff_kernel, dim3(32 * KTOT / 256), dim3(256), 0, stream, woff0, wH0, wL0);
    hipLaunchKernelGGL(prep_woff_kernel, dim3(32 * KTOT / 256), dim3(256), 0, stream, woff1, wH1, wL1);

    // Layer 0: x(NHWC) -> h1t(NHWC)
    hipLaunchKernelGGL(offconv_fused, dim3(288), dim3(256), 0, stream, xt, wH0, wL0, boff0, om);
    hipLaunchKernelGGL(dfconv_fused, dim3(576), dim3(256), 0, stream, xt, om, wA0, h1t, 1);

    // Layer 1: h1t(NHWC) -> out(NCHW)
    hipLaunchKernelGGL(offconv_fused, dim3(288), dim3(256), 0, stream, h1t, wH1, wL1, boff1, om);
    hipLaunchKernelGGL(dfconv_fused, dim3(576), dim3(256), 0, stream, h1t, om, wA1, out, 0);
}

// Round 7
// 546.514 us; speedup vs baseline: 3.3480x; 1.0048x over previous
//
#include <hip/hip_runtime.h>
#include <cstdint>
#include <cstddef>

// DCNv2 x2 (B=2, C=O=256, H=W=96, k=3), fully fused per layer:
//   offconv_fused: standard-3x3 conv via in-LDS im2col, split-bf16 3-term MFMA -> om (fp32 acc)
//   dfconv_fused : deformable sampling into LDS + bf16 MFMA GEMM (+ReLU) -> NHWC h1 / NCHW out
// k' = kk*256 + c. Activations NHWC. XCD swizzle: blockIdx%8 = XCD, contiguous
// image slice per XCD. R7: = R5 kernels + LDS-staged fully-contiguous epilogues
// (R5's interleaved stores caused 8x WRITE_SIZE amplification).

#define KTOT 2304
#define PXB  9216

typedef __attribute__((ext_vector_type(8))) short bf16x8;
typedef __attribute__((ext_vector_type(4))) float f32x4;

static __device__ __forceinline__ unsigned short f2bf(float f) {
    union { float f; unsigned int u; } v; v.f = f;
    unsigned int r = (v.u + 0x7FFFu + ((v.u >> 16) & 1u)) >> 16;
    return (unsigned short)r;
}
static __device__ __forceinline__ float bf2f(unsigned short h) {
    union { unsigned int u; float f; } v; v.u = ((unsigned int)h) << 16;
    return v.f;
}

// ---------------------------------------------------------------------------
// NCHW -> NHWC transpose
// ---------------------------------------------------------------------------
__global__ __launch_bounds__(256) void transpose_kernel(const float* __restrict__ in,
                                                        float* __restrict__ outT) {
    __shared__ float tile[64][65];
    const int hw0 = blockIdx.x * 64;
    const int c0  = blockIdx.y * 64;
    const int b   = blockIdx.z;
    const int lx  = threadIdx.x & 63;
    const int ly  = threadIdx.x >> 6;
#pragma unroll
    for (int i = 0; i < 16; ++i) {
        int cl = ly + i * 4;
        tile[cl][lx] = in[(size_t)(b * 256 + c0 + cl) * PXB + hw0 + lx];
    }
    __syncthreads();
#pragma unroll
    for (int i = 0; i < 16; ++i) {
        int hwl = ly + i * 4;
        outT[((size_t)b * PXB + hw0 + hwl) * 256 + c0 + lx] = tile[lx][hwl];
    }
}

// ---------------------------------------------------------------------------
// Main weight prep: w[o][c][kk] fp32 -> wA[o][k'=kk*256+c] bf16
// ---------------------------------------------------------------------------
__global__ __launch_bounds__(256) void prep_w_kernel(const float* __restrict__ w,
                                                     unsigned short* __restrict__ wA) {
    int idx = blockIdx.x * 256 + threadIdx.x;   // 256*2304
    int o = idx / KTOT;
    int k = idx - o * KTOT;
    int kk = k >> 8;
    int c  = k & 255;
    wA[idx] = f2bf(w[o * KTOT + c * 9 + kk]);
}

// ---------------------------------------------------------------------------
// Offset weight prep (split): rows 27..32 zero. hi = bf16(w), lo = bf16(w-hi).
// ---------------------------------------------------------------------------
__global__ __launch_bounds__(256) void prep_woff_kernel(const float* __restrict__ w,
                                                        unsigned short* __restrict__ wH,
                                                        unsigned short* __restrict__ wL) {
    int idx = blockIdx.x * 256 + threadIdx.x;   // 32*2304
    int o = idx / KTOT;
    int k = idx - o * KTOT;
    int kk = k >> 8;
    int c  = k & 255;
    float f = (o < 27) ? w[o * KTOT + c * 9 + kk] : 0.0f;
    unsigned short hi = f2bf(f);
    wH[idx] = hi;
    wL[idx] = f2bf(f - bf2f(hi));
}

// ---------------------------------------------------------------------------
// Fused offset conv: M=32(27) x N=64px x K=2304, split-bf16 3-term.
// Grid 288, XCD-swizzled. B panel built per K-step in LDS. (R5 verbatim)
// ---------------------------------------------------------------------------
__global__ __launch_bounds__(256) void offconv_fused(const float* __restrict__ xt,
                                                     const unsigned short* __restrict__ AH,
                                                     const unsigned short* __restrict__ AL,
                                                     const float* __restrict__ bias,
                                                     float* __restrict__ om) {
    __shared__ __attribute__((aligned(16))) unsigned short AsH[32 * 72];
    __shared__ __attribute__((aligned(16))) unsigned short AsL[32 * 72];
    __shared__ __attribute__((aligned(16))) unsigned short BsH[64 * 72];
    __shared__ __attribute__((aligned(16))) unsigned short BsL[64 * 72];

    const int tid  = threadIdx.x;
    const int lane = tid & 63, wv = tid >> 6;
    const int quad = lane >> 4, l16 = lane & 15;
    const int g    = blockIdx.x;            // 288
    const int nb   = (g & 7) * 36 + (g >> 3);
    const int n0   = nb * 64;
    const int b    = n0 / PXB;
    const int hw0  = n0 - b * PXB;

    f32x4 acc[2];
#pragma unroll
    for (int mt = 0; mt < 2; ++mt) acc[mt] = (f32x4)0.0f;

    const int arow = tid >> 3, akg = tid & 7;

    for (int kt = 0; kt < 36; ++kt) {
        const int kk = kt >> 2, c0 = (kt & 3) * 64;
        const int dy = kk / 3 - 1, dx = kk - (kk / 3) * 3 - 1;
        __syncthreads();
        {   // stage A (32 rows x 64 k)
            size_t ai = (size_t)arow * KTOT + kt * 64 + akg * 8;
            *(uint4*)&AsH[arow * 72 + akg * 8] = *(const uint4*)&AH[ai];
            *(uint4*)&AsL[arow * 72 + akg * 8] = *(const uint4*)&AL[ai];
        }
        // stage B (64 px x 64 c): 2 tasks/thread
#pragma unroll
        for (int i = 0; i < 2; ++i) {
            int task = i * 256 + tid;
            int px = task >> 3, cg = task & 7;
            int hw = hw0 + px;
            int h = hw / 96, w = hw - h * 96;
            int y = h + dy, x = w + dx;
            bool valid = ((unsigned)y < 96u) && ((unsigned)x < 96u);
            float4 v0 = make_float4(0.f, 0.f, 0.f, 0.f), v1 = v0;
            if (valid) {
                const float* p = xt + ((size_t)b * PXB + y * 96 + x) * 256 + c0 + cg * 8;
                v0 = *(const float4*)p;
                v1 = *(const float4*)(p + 4);
            }
            float vals[8] = {v0.x, v0.y, v0.z, v0.w, v1.x, v1.y, v1.z, v1.w};
            unsigned short hi[8], lo[8];
#pragma unroll
            for (int j = 0; j < 8; ++j) {
                hi[j] = f2bf(vals[j]);
                lo[j] = f2bf(vals[j] - bf2f(hi[j]));
            }
            *(uint4*)&BsH[px * 72 + cg * 8] = *(uint4*)hi;
            *(uint4*)&BsL[px * 72 + cg * 8] = *(uint4*)lo;
        }
        __syncthreads();
#pragma unroll
        for (int ks = 0; ks < 2; ++ks) {
            bf16x8 ah[2], al[2], bh, bl;
#pragma unroll
            for (int mt = 0; mt < 2; ++mt) {
                ah[mt] = *(const bf16x8*)&AsH[(mt * 16 + l16) * 72 + ks * 32 + quad * 8];
                al[mt] = *(const bf16x8*)&AsL[(mt * 16 + l16) * 72 + ks * 32 + quad * 8];
            }
            bh = *(const bf16x8*)&BsH[(wv * 16 + l16) * 72 + ks * 32 + quad * 8];
            bl = *(const bf16x8*)&BsL[(wv * 16 + l16) * 72 + ks * 32 + quad * 8];
#pragma unroll
            for (int mt = 0; mt < 2; ++mt) {
                acc[mt] = __builtin_amdgcn_mfma_f32_16x16x32_bf16(ah[mt], bh, acc[mt], 0, 0, 0);
                acc[mt] = __builtin_amdgcn_mfma_f32_16x16x32_bf16(ah[mt], bl, acc[mt], 0, 0, 0);
                acc[mt] = __builtin_amdgcn_mfma_f32_16x16x32_bf16(al[mt], bh, acc[mt], 0, 0, 0);
            }
        }
    }

#pragma unroll
    for (int mt = 0; mt < 2; ++mt)
#pragma unroll
        for (int r = 0; r < 4; ++r) {
            int m = mt * 16 + quad * 4 + r;
            int n = wv * 16 + l16;
            if (m < 27)
                om[(size_t)(b * 27 + m) * PXB + hw0 + n] = acc[mt][r] + bias[m];
        }
}

// ---------------------------------------------------------------------------
// Fused deformable conv: tile 128m x 64n, full K=2304. Grid 576 (XCD-swizzled:
// each XCD gets 36 consecutive n-blocks x both m-halves, halves adjacent).
// R5 main loop verbatim; NEW: LDS-staged fully-contiguous epilogues.
// ---------------------------------------------------------------------------
__global__ __launch_bounds__(256) void dfconv_fused(const float* __restrict__ xt,
                                                    const float* __restrict__ om,
                                                    const unsigned short* __restrict__ A,
                                                    float* __restrict__ out,
                                                    int out_mode) {
    __shared__ __attribute__((aligned(16))) unsigned short As[128 * 72];
    __shared__ __attribute__((aligned(16))) unsigned short Bs[64 * 72];
    __shared__ __attribute__((aligned(16))) unsigned short goff[576 * 4];
    __shared__ __attribute__((aligned(16))) float gwt[576 * 4];

    const int tid  = threadIdx.x;
    const int lane = tid & 63, wv = tid >> 6;
    const int quad = lane >> 4, l16 = lane & 15;
    const int wn   = wv & 1, wm = wv >> 1;
    // XCD swizzle: g%8 = xcd; s = g/8; nb = xcd*36 + s/2; my = s%2.
    const int g    = blockIdx.x;            // 576
    const int s    = g >> 3;
    const int nb   = (g & 7) * 36 + (s >> 1);
    const int m0   = (s & 1) * 128;
    const int n0   = nb * 64;
    const int b    = n0 / PXB;
    const int hw0  = n0 - b * PXB;

    // ---- geometry: 64 px x 9 taps ----
    for (int task = tid; task < 576; task += 256) {
        int px = task / 9;
        int kk = task - px * 9;
        int hw = hw0 + px;
        int h = hw / 96, w = hw - h * 96;
        const float* omp = om + (size_t)b * 27 * PXB + hw;
        float dy = omp[(size_t)(2 * kk) * PXB];
        float dx = omp[(size_t)(2 * kk + 1) * PXB];
        float mv = omp[(size_t)(18 + kk) * PXB];
        float mk = 1.0f / (1.0f + __expf(-mv));

        float ys = (float)(h + (kk / 3) - 1) + dy;
        float xs = (float)(w + (kk - (kk / 3) * 3) - 1) + dx;
        float fy = floorf(ys), fx = floorf(xs);
        int iy = (int)fy, ix = (int)fx;
        float wy1 = ys - fy, wx1 = xs - fx;
        float wy0 = 1.0f - wy1, wx0 = 1.0f - wx1;
        bool yv0 = (unsigned)iy < 96u, yv1 = (unsigned)(iy + 1) < 96u;
        bool xv0 = (unsigned)ix < 96u, xv1 = (unsigned)(ix + 1) < 96u;
        int y0 = min(max(iy, 0), 95),     y1 = min(max(iy + 1, 0), 95);
        int x0 = min(max(ix, 0), 95),     x1 = min(max(ix + 1, 0), 95);
        int gg = task * 4;
        goff[gg + 0] = (unsigned short)(y0 * 96 + x0);
        goff[gg + 1] = (unsigned short)(y0 * 96 + x1);
        goff[gg + 2] = (unsigned short)(y1 * 96 + x0);
        goff[gg + 3] = (unsigned short)(y1 * 96 + x1);
        gwt[gg + 0] = (yv0 && xv0) ? mk * wy0 * wx0 : 0.0f;
        gwt[gg + 1] = (yv0 && xv1) ? mk * wy0 * wx1 : 0.0f;
        gwt[gg + 2] = (yv1 && xv0) ? mk * wy1 * wx0 : 0.0f;
        gwt[gg + 3] = (yv1 && xv1) ? mk * wy1 * wx1 : 0.0f;
    }

    // ---- A prefetch (kt=0) ----
    const int arow = tid >> 3, akg = tid & 7;
    const unsigned short* Abase = A + (size_t)(m0 + arow) * KTOT + akg * 8;
    uint4 ar[4];
#pragma unroll
    for (int r = 0; r < 4; ++r)
        ar[r] = *(const uint4*)(Abase + (size_t)(r * 32) * KTOT);

    f32x4 acc[4][2];
#pragma unroll
    for (int mt = 0; mt < 4; ++mt)
#pragma unroll
        for (int nt = 0; nt < 2; ++nt) acc[mt][nt] = (f32x4)0.0f;

    __syncthreads();   // geometry ready

    const float* xbase = xt + (size_t)b * PXB * 256;

    for (int kt = 0; kt < 36; ++kt) {
        const int kk = kt >> 2, c0 = (kt & 3) * 64;
        // write A regs to LDS
#pragma unroll
        for (int r = 0; r < 4; ++r)
            *(uint4*)&As[(arow + r * 32) * 72 + akg * 8] = ar[r];
        // sample B (64 px x 64 c): 2 tasks/thread
#pragma unroll
        for (int i = 0; i < 2; ++i) {
            int task = i * 256 + tid;
            int px = task >> 3, cg = task & 7;
            int gg = (px * 9 + kk) * 4;
            ushort4 off4 = *(const ushort4*)&goff[gg];
            float4  wt   = *(const float4*)&gwt[gg];
            const float* cb = xbase + c0 + cg * 8;
            const float* p0 = cb + (size_t)off4.x * 256;
            const float* p1 = cb + (size_t)off4.y * 256;
            const float* p2 = cb + (size_t)off4.z * 256;
            const float* p3 = cb + (size_t)off4.w * 256;
            float4 q0 = *(const float4*)p0, q1 = *(const float4*)p1;
            float4 q2 = *(const float4*)p2, q3 = *(const float4*)p3;
            float4 r0 = *(const float4*)(p0 + 4), r1 = *(const float4*)(p1 + 4);
            float4 r2 = *(const float4*)(p2 + 4), r3 = *(const float4*)(p3 + 4);
            unsigned short res[8];
            res[0] = f2bf(wt.x*q0.x + wt.y*q1.x + wt.z*q2.x + wt.w*q3.x);
            res[1] = f2bf(wt.x*q0.y + wt.y*q1.y + wt.z*q2.y + wt.w*q3.y);
            res[2] = f2bf(wt.x*q0.z + wt.y*q1.z + wt.z*q2.z + wt.w*q3.z);
            res[3] = f2bf(wt.x*q0.w + wt.y*q1.w + wt.z*q2.w + wt.w*q3.w);
            res[4] = f2bf(wt.x*r0.x + wt.y*r1.x + wt.z*r2.x + wt.w*r3.x);
            res[5] = f2bf(wt.x*r0.y + wt.y*r1.y + wt.z*r2.y + wt.w*r3.y);
            res[6] = f2bf(wt.x*r0.z + wt.y*r1.z + wt.z*r2.z + wt.w*r3.z);
            res[7] = f2bf(wt.x*r0.w + wt.y*r1.w + wt.z*r2.w + wt.w*r3.w);
            *(uint4*)&Bs[px * 72 + cg * 8] = *(uint4*)res;
        }
        __syncthreads();
        // prefetch next A chunk
        if (kt + 1 < 36) {
#pragma unroll
            for (int r = 0; r < 4; ++r)
                ar[r] = *(const uint4*)(Abase + (kt + 1) * 64 + (size_t)(r * 32) * KTOT);
        }
        // MFMA
#pragma unroll
        for (int ks = 0; ks < 2; ++ks) {
            bf16x8 af[4], bfr[2];
#pragma unroll
            for (int mt = 0; mt < 4; ++mt)
                af[mt] = *(const bf16x8*)&As[(wm * 64 + mt * 16 + l16) * 72 + ks * 32 + quad * 8];
#pragma unroll
            for (int nt = 0; nt < 2; ++nt)
                bfr[nt] = *(const bf16x8*)&Bs[(wn * 32 + nt * 16 + l16) * 72 + ks * 32 + quad * 8];
#pragma unroll
            for (int mt = 0; mt < 4; ++mt)
#pragma unroll
                for (int nt = 0; nt < 2; ++nt)
                    acc[mt][nt] = __builtin_amdgcn_mfma_f32_16x16x32_bf16(
                        af[mt], bfr[nt], acc[mt][nt], 0, 0, 0);
        }
        __syncthreads();
    }

    // ---- NEW epilogues: LDS-staged, every store instruction covers full
    //      contiguous wave-blocks (fixes 8x WRITE_SIZE amplification) ----
    float* tile = (float*)As;    // 18432 B available
    if (out_mode == 0) {
        // NCHW out[b][m][hw]: 2 passes of 64 m x 64 n; tile stride 68
        // (68*4=272 B; float4 reads stay 16B-aligned: row*272 + q*16).
#pragma unroll
        for (int pass = 0; pass < 2; ++pass) {
            __syncthreads();
            if (wm == pass) {
#pragma unroll
                for (int mt = 0; mt < 4; ++mt)
#pragma unroll
                    for (int nt = 0; nt < 2; ++nt)
#pragma unroll
                        for (int r = 0; r < 4; ++r) {
                            int ml = mt * 16 + quad * 4 + r;      // 0..63
                            int n  = wn * 32 + nt * 16 + l16;     // 0..63
                            tile[ml * 68 + n] = fmaxf(acc[mt][nt][r], 0.0f);
                        }
            }
            __syncthreads();
#pragma unroll
            for (int j = 0; j < 4; ++j) {
                int idx = j * 256 + tid;          // 1024 float4s = 64m x 16q
                int row = idx >> 4, q = idx & 15;
                int m = m0 + pass * 64 + row;
                *(float4*)&out[(size_t)(b * 256 + m) * PXB + hw0 + q * 4] =
                    *(const float4*)&tile[row * 68 + q * 4];
            }
        }
    } else {
        // NHWC out[b][hw][m0+..]: 2 passes of 32 px x 128 ch; tile stride 132.
#pragma unroll
        for (int pass = 0; pass < 2; ++pass) {
            __syncthreads();
            if (wn == pass) {
#pragma unroll
                for (int mt = 0; mt < 4; ++mt)
#pragma unroll
                    for (int nt = 0; nt < 2; ++nt) {
                        int row = nt * 16 + l16;                  // 0..31
                        int col = wm * 64 + mt * 16 + quad * 4;   // 0..127
                        f32x4 v = acc[mt][nt];
                        v[0] = fmaxf(v[0], 0.f); v[1] = fmaxf(v[1], 0.f);
                        v[2] = fmaxf(v[2], 0.f); v[3] = fmaxf(v[3], 0.f);
                        *(f32x4*)&tile[row * 132 + col] = v;
                    }
            }
            __syncthreads();
#pragma unroll
            for (int j = 0; j < 4; ++j) {
                int idx = j * 256 + tid;          // 1024 float4s = 32px x 32
                int pxl = idx >> 5, ln = idx & 31;
                *(float4*)&out[((size_t)b * PXB + hw0 + pass * 32 + pxl) * 256 + m0 + ln * 4] =
                    *(const float4*)&tile[pxl * 132 + ln * 4];
            }
        }
    }
}

// ---------------------------------------------------------------------------
extern "C" void kernel_launch(void* const* d_in, const int* in_sizes, int n_in,
                              void* d_out, int out_size, void* d_ws, size_t ws_size,
                              hipStream_t stream) {
    const float* x     = (const float*)d_in[0];
    const float* woff0 = (const float*)d_in[1];
    const float* boff0 = (const float*)d_in[2];
    const float* w0    = (const float*)d_in[3];
    const float* woff1 = (const float*)d_in[4];
    const float* boff1 = (const float*)d_in[5];
    const float* w1    = (const float*)d_in[6];
    float* out = (float*)d_out;

    char* p = (char*)d_ws;
    float* om  = (float*)p;  p += (size_t)2 * 27 * PXB * 4;               // 2.0 MB
    float* xt  = (float*)p;  p += (size_t)2 * 256 * PXB * 4;              // 18.9 MB
    float* h1t = (float*)p;  p += (size_t)2 * 256 * PXB * 4;              // 18.9 MB
    unsigned short* wA0 = (unsigned short*)p; p += (size_t)256 * KTOT * 2;
    unsigned short* wA1 = (unsigned short*)p; p += (size_t)256 * KTOT * 2;
    unsigned short* wH0 = (unsigned short*)p; p += (size_t)32 * KTOT * 2;
    unsigned short* wL0 = (unsigned short*)p; p += (size_t)32 * KTOT * 2;
    unsigned short* wH1 = (unsigned short*)p; p += (size_t)32 * KTOT * 2;
    unsigned short* wL1 = (unsigned short*)p; p += (size_t)32 * KTOT * 2;

    hipLaunchKernelGGL(transpose_kernel, dim3(PXB / 64, 4, 2), dim3(256), 0, stream, x, xt);
    hipLaunchKernelGGL(prep_w_kernel, dim3(256 * KTOT / 256), dim3(256), 0, stream, w0, wA0);
    hipLaunchKernelGGL(prep_w_kernel, dim3(256 * KTOT / 256), dim3(256), 0, stream, w1, wA1);
    hipLaunchKernelGGL(prep_woff_kernel, dim3(32 * KTOT / 256), dim3(256), 0, stream, woff0, wH0, wL0);
    hipLaunchKernelGGL(prep_woff_kernel, dim3(32 * KTOT / 256), dim3(256), 0, stream, woff1, wH1, wL1);

    // Layer 0: x(NHWC) -> h1t(NHWC)
    hipLaunchKernelGGL(offconv_fused, dim3(288), dim3(256), 0, stream, xt, wH0, wL0, boff0, om);
    hipLaunchKernelGGL(dfconv_fused, dim3(576), dim3(256), 0, stream, xt, om, wA0, h1t, 1);

    // Layer 1: h1t(NHWC) -> out(NCHW)
    hipLaunchKernelGGL(offconv_fused, dim3(288), dim3(256), 0, stream, h1t, wH1, wL1, boff1, om);
    hipLaunchKernelGGL(dfconv_fused, dim3(576), dim3(256), 0, stream, h1t, om, wA1, out, 0);
}

// Round 8
// 508.305 us; speedup vs baseline: 3.5996x; 1.0752x over previous
//
#include <hip/hip_runtime.h>
#include <cstdint>
#include <cstddef>

// DCNv2 x2 (B=2, C=O=256, H=W=96, k=3), fully fused per layer:
//   offconv_fused: standard-3x3 conv via in-LDS im2col, split-bf16 3-term MFMA -> om (R7 verbatim)
//   dfconv_fused : deformable sampling + bf16 MFMA GEMM; R8: 2-deep software
//                  pipeline (gather for kt+1 issued before MFMA of kt; B LDS
//                  double-buffered; A fragments direct-from-global registers).
// k' = kk*256 + c. Activations NHWC. XCD swizzle: blockIdx%8 = XCD, contiguous
// image slice per XCD.

#define KTOT 2304
#define PXB  9216

typedef __attribute__((ext_vector_type(8))) short bf16x8;
typedef __attribute__((ext_vector_type(4))) float f32x4;

static __device__ __forceinline__ unsigned short f2bf(float f) {
    union { float f; unsigned int u; } v; v.f = f;
    unsigned int r = (v.u + 0x7FFFu + ((v.u >> 16) & 1u)) >> 16;
    return (unsigned short)r;
}
static __device__ __forceinline__ float bf2f(unsigned short h) {
    union { unsigned int u; float f; } v; v.u = ((unsigned int)h) << 16;
    return v.f;
}

// ---------------------------------------------------------------------------
// NCHW -> NHWC transpose
// ---------------------------------------------------------------------------
__global__ __launch_bounds__(256) void transpose_kernel(const float* __restrict__ in,
                                                        float* __restrict__ outT) {
    __shared__ float tile[64][65];
    const int hw0 = blockIdx.x * 64;
    const int c0  = blockIdx.y * 64;
    const int b   = blockIdx.z;
    const int lx  = threadIdx.x & 63;
    const int ly  = threadIdx.x >> 6;
#pragma unroll
    for (int i = 0; i < 16; ++i) {
        int cl = ly + i * 4;
        tile[cl][lx] = in[(size_t)(b * 256 + c0 + cl) * PXB + hw0 + lx];
    }
    __syncthreads();
#pragma unroll
    for (int i = 0; i < 16; ++i) {
        int hwl = ly + i * 4;
        outT[((size_t)b * PXB + hw0 + hwl) * 256 + c0 + lx] = tile[lx][hwl];
    }
}

// ---------------------------------------------------------------------------
// Main weight prep: w[o][c][kk] fp32 -> wA[o][k'=kk*256+c] bf16
// ---------------------------------------------------------------------------
__global__ __launch_bounds__(256) void prep_w_kernel(const float* __restrict__ w,
                                                     unsigned short* __restrict__ wA) {
    int idx = blockIdx.x * 256 + threadIdx.x;   // 256*2304
    int o = idx / KTOT;
    int k = idx - o * KTOT;
    int kk = k >> 8;
    int c  = k & 255;
    wA[idx] = f2bf(w[o * KTOT + c * 9 + kk]);
}

// ---------------------------------------------------------------------------
// Offset weight prep (split): rows 27..32 zero. hi = bf16(w), lo = bf16(w-hi).
// ---------------------------------------------------------------------------
__global__ __launch_bounds__(256) void prep_woff_kernel(const float* __restrict__ w,
                                                        unsigned short* __restrict__ wH,
                                                        unsigned short* __restrict__ wL) {
    int idx = blockIdx.x * 256 + threadIdx.x;   // 32*2304
    int o = idx / KTOT;
    int k = idx - o * KTOT;
    int kk = k >> 8;
    int c  = k & 255;
    float f = (o < 27) ? w[o * KTOT + c * 9 + kk] : 0.0f;
    unsigned short hi = f2bf(f);
    wH[idx] = hi;
    wL[idx] = f2bf(f - bf2f(hi));
}

// ---------------------------------------------------------------------------
// Fused offset conv: M=32(27) x N=64px x K=2304, split-bf16 3-term.
// Grid 288, XCD-swizzled. (R7 verbatim)
// ---------------------------------------------------------------------------
__global__ __launch_bounds__(256) void offconv_fused(const float* __restrict__ xt,
                                                     const unsigned short* __restrict__ AH,
                                                     const unsigned short* __restrict__ AL,
                                                     const float* __restrict__ bias,
                                                     float* __restrict__ om) {
    __shared__ __attribute__((aligned(16))) unsigned short AsH[32 * 72];
    __shared__ __attribute__((aligned(16))) unsigned short AsL[32 * 72];
    __shared__ __attribute__((aligned(16))) unsigned short BsH[64 * 72];
    __shared__ __attribute__((aligned(16))) unsigned short BsL[64 * 72];

    const int tid  = threadIdx.x;
    const int lane = tid & 63, wv = tid >> 6;
    const int quad = lane >> 4, l16 = lane & 15;
    const int g    = blockIdx.x;            // 288
    const int nb   = (g & 7) * 36 + (g >> 3);
    const int n0   = nb * 64;
    const int b    = n0 / PXB;
    const int hw0  = n0 - b * PXB;

    f32x4 acc[2];
#pragma unroll
    for (int mt = 0; mt < 2; ++mt) acc[mt] = (f32x4)0.0f;

    const int arow = tid >> 3, akg = tid & 7;

    for (int kt = 0; kt < 36; ++kt) {
        const int kk = kt >> 2, c0 = (kt & 3) * 64;
        const int dy = kk / 3 - 1, dx = kk - (kk / 3) * 3 - 1;
        __syncthreads();
        {   // stage A (32 rows x 64 k)
            size_t ai = (size_t)arow * KTOT + kt * 64 + akg * 8;
            *(uint4*)&AsH[arow * 72 + akg * 8] = *(const uint4*)&AH[ai];
            *(uint4*)&AsL[arow * 72 + akg * 8] = *(const uint4*)&AL[ai];
        }
        // stage B (64 px x 64 c): 2 tasks/thread
#pragma unroll
        for (int i = 0; i < 2; ++i) {
            int task = i * 256 + tid;
            int px = task >> 3, cg = task & 7;
            int hw = hw0 + px;
            int h = hw / 96, w = hw - h * 96;
            int y = h + dy, x = w + dx;
            bool valid = ((unsigned)y < 96u) && ((unsigned)x < 96u);
            float4 v0 = make_float4(0.f, 0.f, 0.f, 0.f), v1 = v0;
            if (valid) {
                const float* p = xt + ((size_t)b * PXB + y * 96 + x) * 256 + c0 + cg * 8;
                v0 = *(const float4*)p;
                v1 = *(const float4*)(p + 4);
            }
            float vals[8] = {v0.x, v0.y, v0.z, v0.w, v1.x, v1.y, v1.z, v1.w};
            unsigned short hi[8], lo[8];
#pragma unroll
            for (int j = 0; j < 8; ++j) {
                hi[j] = f2bf(vals[j]);
                lo[j] = f2bf(vals[j] - bf2f(hi[j]));
            }
            *(uint4*)&BsH[px * 72 + cg * 8] = *(uint4*)hi;
            *(uint4*)&BsL[px * 72 + cg * 8] = *(uint4*)lo;
        }
        __syncthreads();
#pragma unroll
        for (int ks = 0; ks < 2; ++ks) {
            bf16x8 ah[2], al[2], bh, bl;
#pragma unroll
            for (int mt = 0; mt < 2; ++mt) {
                ah[mt] = *(const bf16x8*)&AsH[(mt * 16 + l16) * 72 + ks * 32 + quad * 8];
                al[mt] = *(const bf16x8*)&AsL[(mt * 16 + l16) * 72 + ks * 32 + quad * 8];
            }
            bh = *(const bf16x8*)&BsH[(wv * 16 + l16) * 72 + ks * 32 + quad * 8];
            bl = *(const bf16x8*)&BsL[(wv * 16 + l16) * 72 + ks * 32 + quad * 8];
#pragma unroll
            for (int mt = 0; mt < 2; ++mt) {
                acc[mt] = __builtin_amdgcn_mfma_f32_16x16x32_bf16(ah[mt], bh, acc[mt], 0, 0, 0);
                acc[mt] = __builtin_amdgcn_mfma_f32_16x16x32_bf16(ah[mt], bl, acc[mt], 0, 0, 0);
                acc[mt] = __builtin_amdgcn_mfma_f32_16x16x32_bf16(al[mt], bh, acc[mt], 0, 0, 0);
            }
        }
    }

#pragma unroll
    for (int mt = 0; mt < 2; ++mt)
#pragma unroll
        for (int r = 0; r < 4; ++r) {
            int m = mt * 16 + quad * 4 + r;
            int n = wv * 16 + l16;
            if (m < 27)
                om[(size_t)(b * 27 + m) * PXB + hw0 + n] = acc[mt][r] + bias[m];
        }
}

// ---------------------------------------------------------------------------
// Fused deformable conv: tile 128m x 64n, K=2304, grid 576 (R7 swizzle).
// R8 pipelined K-loop: A fragments direct-from-global (L2-hot, issued first);
// gather for kt+1 issued before MFMA of kt; B LDS double-buffered; one
// barrier per iteration. Epilogues = R7 (staging reuses Bs).
// ---------------------------------------------------------------------------
__global__ __launch_bounds__(256) void dfconv_fused(const float* __restrict__ xt,
                                                    const float* __restrict__ om,
                                                    const unsigned short* __restrict__ A,
                                                    float* __restrict__ out,
                                                    int out_mode) {
    __shared__ __attribute__((aligned(16))) unsigned short Bs[2][64 * 72];
    __shared__ __attribute__((aligned(16))) unsigned short goff[576 * 4];
    __shared__ __attribute__((aligned(16))) float gwt[576 * 4];

    const int tid  = threadIdx.x;
    const int lane = tid & 63, wv = tid >> 6;
    const int quad = lane >> 4, l16 = lane & 15;
    const int wn   = wv & 1, wm = wv >> 1;
    // XCD swizzle: g%8 = xcd; s = g/8; nb = xcd*36 + s/2; m-half = s%2.
    const int g    = blockIdx.x;            // 576
    const int s    = g >> 3;
    const int nb   = (g & 7) * 36 + (s >> 1);
    const int m0   = (s & 1) * 128;
    const int n0   = nb * 64;
    const int b    = n0 / PXB;
    const int hw0  = n0 - b * PXB;

    // ---- geometry: 64 px x 9 taps ----
    for (int task = tid; task < 576; task += 256) {
        int px = task / 9;
        int kk = task - px * 9;
        int hw = hw0 + px;
        int h = hw / 96, w = hw - h * 96;
        const float* omp = om + (size_t)b * 27 * PXB + hw;
        float dy = omp[(size_t)(2 * kk) * PXB];
        float dx = omp[(size_t)(2 * kk + 1) * PXB];
        float mv = omp[(size_t)(18 + kk) * PXB];
        float mk = 1.0f / (1.0f + __expf(-mv));

        float ys = (float)(h + (kk / 3) - 1) + dy;
        float xs = (float)(w + (kk - (kk / 3) * 3) - 1) + dx;
        float fy = floorf(ys), fx = floorf(xs);
        int iy = (int)fy, ix = (int)fx;
        float wy1 = ys - fy, wx1 = xs - fx;
        float wy0 = 1.0f - wy1, wx0 = 1.0f - wx1;
        bool yv0 = (unsigned)iy < 96u, yv1 = (unsigned)(iy + 1) < 96u;
        bool xv0 = (unsigned)ix < 96u, xv1 = (unsigned)(ix + 1) < 96u;
        int y0 = min(max(iy, 0), 95),     y1 = min(max(iy + 1, 0), 95);
        int x0 = min(max(ix, 0), 95),     x1 = min(max(ix + 1, 0), 95);
        int gg = task * 4;
        goff[gg + 0] = (unsigned short)(y0 * 96 + x0);
        goff[gg + 1] = (unsigned short)(y0 * 96 + x1);
        goff[gg + 2] = (unsigned short)(y1 * 96 + x0);
        goff[gg + 3] = (unsigned short)(y1 * 96 + x1);
        gwt[gg + 0] = (yv0 && xv0) ? mk * wy0 * wx0 : 0.0f;
        gwt[gg + 1] = (yv0 && xv1) ? mk * wy0 * wx1 : 0.0f;
        gwt[gg + 2] = (yv1 && xv0) ? mk * wy1 * wx0 : 0.0f;
        gwt[gg + 3] = (yv1 && xv1) ? mk * wy1 * wx1 : 0.0f;
    }

    f32x4 acc[4][2];
#pragma unroll
    for (int mt = 0; mt < 4; ++mt)
#pragma unroll
        for (int nt = 0; nt < 2; ++nt) acc[mt][nt] = (f32x4)0.0f;

    __syncthreads();   // geometry ready

    const int gpx = tid >> 3, gcg = tid & 7;       // gather task decomposition
    const float* xbase = xt + (size_t)b * PXB * 256 + gcg * 8;
    const unsigned short* Arow = A + (size_t)(m0 + wm * 64 + l16) * KTOT + quad * 8;

    // ---- prologue: gather panel kt=0 (kk=0, c0=0) -> Bs[0] ----
#pragma unroll
    for (int i = 0; i < 2; ++i) {
        int px = gpx + i * 32;
        int gg = (px * 9 + 0) * 4;
        ushort4 o4 = *(const ushort4*)&goff[gg];
        float4  wt = *(const float4*)&gwt[gg];
        const float* p0 = xbase + (size_t)o4.x * 256;
        const float* p1 = xbase + (size_t)o4.y * 256;
        const float* p2 = xbase + (size_t)o4.z * 256;
        const float* p3 = xbase + (size_t)o4.w * 256;
        float4 q0 = *(const float4*)p0, q1 = *(const float4*)p1;
        float4 q2 = *(const float4*)p2, q3 = *(const float4*)p3;
        float4 r0 = *(const float4*)(p0 + 4), r1 = *(const float4*)(p1 + 4);
        float4 r2 = *(const float4*)(p2 + 4), r3 = *(const float4*)(p3 + 4);
        unsigned short res[8];
        res[0] = f2bf(wt.x*q0.x + wt.y*q1.x + wt.z*q2.x + wt.w*q3.x);
        res[1] = f2bf(wt.x*q0.y + wt.y*q1.y + wt.z*q2.y + wt.w*q3.y);
        res[2] = f2bf(wt.x*q0.z + wt.y*q1.z + wt.z*q2.z + wt.w*q3.z);
        res[3] = f2bf(wt.x*q0.w + wt.y*q1.w + wt.z*q2.w + wt.w*q3.w);
        res[4] = f2bf(wt.x*r0.x + wt.y*r1.x + wt.z*r2.x + wt.w*r3.x);
        res[5] = f2bf(wt.x*r0.y + wt.y*r1.y + wt.z*r2.y + wt.w*r3.y);
        res[6] = f2bf(wt.x*r0.z + wt.y*r1.z + wt.z*r2.z + wt.w*r3.z);
        res[7] = f2bf(wt.x*r0.w + wt.y*r1.w + wt.z*r2.w + wt.w*r3.w);
        *(uint4*)&Bs[0][px * 72 + gcg * 8] = *(uint4*)res;
    }
    __syncthreads();   // Bs[0] ready

    for (int kt = 0; kt < 36; ++kt) {
        const int cur = kt & 1;
        // (1) A fragments for kt — issued FIRST so MFMA's vmcnt wait covers
        //     only these (L2-hot panel shared by the whole XCD).
        bf16x8 af[2][4];
#pragma unroll
        for (int ks = 0; ks < 2; ++ks)
#pragma unroll
            for (int mt = 0; mt < 4; ++mt)
                af[ks][mt] = *(const bf16x8*)(Arow + (size_t)(mt * 16) * KTOT + kt * 64 + ks * 32);

        // (2) issue gather loads for kt+1 (stay in flight across the MFMAs)
        float4 gq[2][8]; float4 gw[2];
        if (kt < 35) {
            const int kkn = (kt + 1) >> 2;
            const int c0n = ((kt + 1) & 3) * 64;
#pragma unroll
            for (int i = 0; i < 2; ++i) {
                int px = gpx + i * 32;
                int gg = (px * 9 + kkn) * 4;
                ushort4 o4 = *(const ushort4*)&goff[gg];
                gw[i] = *(const float4*)&gwt[gg];
                const float* cb = xbase + c0n;
                const float* p0 = cb + (size_t)o4.x * 256;
                const float* p1 = cb + (size_t)o4.y * 256;
                const float* p2 = cb + (size_t)o4.z * 256;
                const float* p3 = cb + (size_t)o4.w * 256;
                gq[i][0] = *(const float4*)p0;       gq[i][1] = *(const float4*)p1;
                gq[i][2] = *(const float4*)p2;       gq[i][3] = *(const float4*)p3;
                gq[i][4] = *(const float4*)(p0 + 4); gq[i][5] = *(const float4*)(p1 + 4);
                gq[i][6] = *(const float4*)(p2 + 4); gq[i][7] = *(const float4*)(p3 + 4);
            }
        }

        // (3) MFMA phase: A from regs (waits only A loads), B from Bs[cur]
#pragma unroll
        for (int ks = 0; ks < 2; ++ks) {
            bf16x8 bfr[2];
#pragma unroll
            for (int nt = 0; nt < 2; ++nt)
                bfr[nt] = *(const bf16x8*)&Bs[cur][(wn * 32 + nt * 16 + l16) * 72 + ks * 32 + quad * 8];
#pragma unroll
            for (int mt = 0; mt < 4; ++mt)
#pragma unroll
                for (int nt = 0; nt < 2; ++nt)
                    acc[mt][nt] = __builtin_amdgcn_mfma_f32_16x16x32_bf16(
                        af[ks][mt], bfr[nt], acc[mt][nt], 0, 0, 0);
        }

        // (4) convert + write next panel to the other buffer
        if (kt < 35) {
#pragma unroll
            for (int i = 0; i < 2; ++i) {
                int px = gpx + i * 32;
                float4 wt = gw[i];
                unsigned short res[8];
                res[0] = f2bf(wt.x*gq[i][0].x + wt.y*gq[i][1].x + wt.z*gq[i][2].x + wt.w*gq[i][3].x);
                res[1] = f2bf(wt.x*gq[i][0].y + wt.y*gq[i][1].y + wt.z*gq[i][2].y + wt.w*gq[i][3].y);
                res[2] = f2bf(wt.x*gq[i][0].z + wt.y*gq[i][1].z + wt.z*gq[i][2].z + wt.w*gq[i][3].z);
                res[3] = f2bf(wt.x*gq[i][0].w + wt.y*gq[i][1].w + wt.z*gq[i][2].w + wt.w*gq[i][3].w);
                res[4] = f2bf(wt.x*gq[i][4].x + wt.y*gq[i][5].x + wt.z*gq[i][6].x + wt.w*gq[i][7].x);
                res[5] = f2bf(wt.x*gq[i][4].y + wt.y*gq[i][5].y + wt.z*gq[i][6].y + wt.w*gq[i][7].y);
                res[6] = f2bf(wt.x*gq[i][4].z + wt.y*gq[i][5].z + wt.z*gq[i][6].z + wt.w*gq[i][7].z);
                res[7] = f2bf(wt.x*gq[i][4].w + wt.y*gq[i][5].w + wt.z*gq[i][6].w + wt.w*gq[i][7].w);
                *(uint4*)&Bs[cur ^ 1][px * 72 + gcg * 8] = *(uint4*)res;
            }
        }
        __syncthreads();
    }

    // ---- epilogues (R7 verbatim, staging reuses Bs) ----
    float* tile = (float*)Bs;
    if (out_mode == 0) {
        // NCHW out[b][m][hw]: 2 passes of 64 m x 64 n; tile stride 68.
#pragma unroll
        for (int pass = 0; pass < 2; ++pass) {
            __syncthreads();
            if (wm == pass) {
#pragma unroll
                for (int mt = 0; mt < 4; ++mt)
#pragma unroll
                    for (int nt = 0; nt < 2; ++nt)
#pragma unroll
                        for (int r = 0; r < 4; ++r) {
                            int ml = mt * 16 + quad * 4 + r;      // 0..63
                            int n  = wn * 32 + nt * 16 + l16;     // 0..63
                            tile[ml * 68 + n] = fmaxf(acc[mt][nt][r], 0.0f);
                        }
            }
            __syncthreads();
#pragma unroll
            for (int j = 0; j < 4; ++j) {
                int idx = j * 256 + tid;          // 1024 float4s = 64m x 16q
                int row = idx >> 4, q = idx & 15;
                int m = m0 + pass * 64 + row;
                *(float4*)&out[(size_t)(b * 256 + m) * PXB + hw0 + q * 4] =
                    *(const float4*)&tile[row * 68 + q * 4];
            }
        }
    } else {
        // NHWC out[b][hw][m0+..]: 2 passes of 32 px x 128 ch; tile stride 132.
#pragma unroll
        for (int pass = 0; pass < 2; ++pass) {
            __syncthreads();
            if (wn == pass) {
#pragma unroll
                for (int mt = 0; mt < 4; ++mt)
#pragma unroll
                    for (int nt = 0; nt < 2; ++nt) {
                        int row = nt * 16 + l16;                  // 0..31
                        int col = wm * 64 + mt * 16 + quad * 4;   // 0..127
                        f32x4 v = acc[mt][nt];
                        v[0] = fmaxf(v[0], 0.f); v[1] = fmaxf(v[1], 0.f);
                        v[2] = fmaxf(v[2], 0.f); v[3] = fmaxf(v[3], 0.f);
                        *(f32x4*)&tile[row * 132 + col] = v;
                    }
            }
            __syncthreads();
#pragma unroll
            for (int j = 0; j < 4; ++j) {
                int idx = j * 256 + tid;          // 1024 float4s = 32px x 32
                int pxl = idx >> 5, ln = idx & 31;
                *(float4*)&out[((size_t)b * PXB + hw0 + pass * 32 + pxl) * 256 + m0 + ln * 4] =
                    *(const float4*)&tile[pxl * 132 + ln * 4];
            }
        }
    }
}

// ---------------------------------------------------------------------------
extern "C" void kernel_launch(void* const* d_in, const int* in_sizes, int n_in,
                              void* d_out, int out_size, void* d_ws, size_t ws_size,
                              hipStream_t stream) {
    const float* x     = (const float*)d_in[0];
    const float* woff0 = (const float*)d_in[1];
    const float* boff0 = (const float*)d_in[2];
    const float* w0    = (const float*)d_in[3];
    const float* woff1 = (const float*)d_in[4];
    const float* boff1 = (const float*)d_in[5];
    const float* w1    = (const float*)d_in[6];
    float* out = (float*)d_out;

    char* p = (char*)d_ws;
    float* om  = (float*)p;  p += (size_t)2 * 27 * PXB * 4;               // 2.0 MB
    float* xt  = (float*)p;  p += (size_t)2 * 256 * PXB * 4;              // 18.9 MB
    float* h1t = (float*)p;  p += (size_t)2 * 256 * PXB * 4;              // 18.9 MB
    unsigned short* wA0 = (unsigned short*)p; p += (size_t)256 * KTOT * 2;
    unsigned short* wA1 = (unsigned short*)p; p += (size_t)256 * KTOT * 2;
    unsigned short* wH0 = (unsigned short*)p; p += (size_t)32 * KTOT * 2;
    unsigned short* wL0 = (unsigned short*)p; p += (size_t)32 * KTOT * 2;
    unsigned short* wH1 = (unsigned short*)p; p += (size_t)32 * KTOT * 2;
    unsigned short* wL1 = (unsigned short*)p; p += (size_t)32 * KTOT * 2;

    hipLaunchKernelGGL(transpose_kernel, dim3(PXB / 64, 4, 2), dim3(256), 0, stream, x, xt);
    hipLaunchKernelGGL(prep_w_kernel, dim3(256 * KTOT / 256), dim3(256), 0, stream, w0, wA0);
    hipLaunchKernelGGL(prep_w_kernel, dim3(256 * KTOT / 256), dim3(256), 0, stream, w1, wA1);
    hipLaunchKernelGGL(prep_woff_kernel, dim3(32 * KTOT / 256), dim3(256), 0, stream, woff0, wH0, wL0);
    hipLaunchKernelGGL(prep_woff_kernel, dim3(32 * KTOT / 256), dim3(256), 0, stream, woff1, wH1, wL1);

    // Layer 0: x(NHWC) -> h1t(NHWC)
    hipLaunchKernelGGL(offconv_fused, dim3(288), dim3(256), 0, stream, xt, wH0, wL0, boff0, om);
    hipLaunchKernelGGL(dfconv_fused, dim3(576), dim3(256), 0, stream, xt, om, wA0, h1t, 1);

    // Layer 1: h1t(NHWC) -> out(NCHW)
    hipLaunchKernelGGL(offconv_fused, dim3(288), dim3(256), 0, stream, h1t, wH1, wL1, boff1, om);
    hipLaunchKernelGGL(dfconv_fused, dim3(576), dim3(256), 0, stream, h1t, om, wA1, out, 0);
}

// Round 9
// 491.859 us; speedup vs baseline: 3.7200x; 1.0334x over previous
//
#include <hip/hip_runtime.h>
#include <cstdint>
#include <cstddef>

// DCNv2 x2 (B=2, C=O=256, H=W=96, k=3), fully fused per layer.
// R9: 512-thread blocks with IN-BLOCK SPLIT-K (waves 0-3 = K-half 0, waves
// 4-7 = K-half 1, each with private LDS B panels + accumulators; LDS
// reduction at the end). Raises resident waves/CU from ~5.7 to ~18 to
// overlap the barrier-coupled gather stalls (R8 post-mortem: compiler
// early-waits the gather, so ILP pipelining is defeated; TLP is the lever).
// k' = kk*256 + c. Activations NHWC. XCD swizzle: blockIdx%8 = XCD.

#define KTOT 2304
#define PXB  9216

typedef __attribute__((ext_vector_type(8))) short bf16x8;
typedef __attribute__((ext_vector_type(4))) float f32x4;

static __device__ __forceinline__ unsigned short f2bf(float f) {
    union { float f; unsigned int u; } v; v.f = f;
    unsigned int r = (v.u + 0x7FFFu + ((v.u >> 16) & 1u)) >> 16;
    return (unsigned short)r;
}
static __device__ __forceinline__ float bf2f(unsigned short h) {
    union { unsigned int u; float f; } v; v.u = ((unsigned int)h) << 16;
    return v.f;
}

// ---------------------------------------------------------------------------
// NCHW -> NHWC transpose
// ---------------------------------------------------------------------------
__global__ __launch_bounds__(256) void transpose_kernel(const float* __restrict__ in,
                                                        float* __restrict__ outT) {
    __shared__ float tile[64][65];
    const int hw0 = blockIdx.x * 64;
    const int c0  = blockIdx.y * 64;
    const int b   = blockIdx.z;
    const int lx  = threadIdx.x & 63;
    const int ly  = threadIdx.x >> 6;
#pragma unroll
    for (int i = 0; i < 16; ++i) {
        int cl = ly + i * 4;
        tile[cl][lx] = in[(size_t)(b * 256 + c0 + cl) * PXB + hw0 + lx];
    }
    __syncthreads();
#pragma unroll
    for (int i = 0; i < 16; ++i) {
        int hwl = ly + i * 4;
        outT[((size_t)b * PXB + hw0 + hwl) * 256 + c0 + lx] = tile[lx][hwl];
    }
}

// ---------------------------------------------------------------------------
// Main weight prep: w[o][c][kk] fp32 -> wA[o][k'=kk*256+c] bf16
// ---------------------------------------------------------------------------
__global__ __launch_bounds__(256) void prep_w_kernel(const float* __restrict__ w,
                                                     unsigned short* __restrict__ wA) {
    int idx = blockIdx.x * 256 + threadIdx.x;   // 256*2304
    int o = idx / KTOT;
    int k = idx - o * KTOT;
    int kk = k >> 8;
    int c  = k & 255;
    wA[idx] = f2bf(w[o * KTOT + c * 9 + kk]);
}

// ---------------------------------------------------------------------------
// Offset weight prep (split): rows 27..32 zero. hi = bf16(w), lo = bf16(w-hi).
// ---------------------------------------------------------------------------
__global__ __launch_bounds__(256) void prep_woff_kernel(const float* __restrict__ w,
                                                        unsigned short* __restrict__ wH,
                                                        unsigned short* __restrict__ wL) {
    int idx = blockIdx.x * 256 + threadIdx.x;   // 32*2304
    int o = idx / KTOT;
    int k = idx - o * KTOT;
    int kk = k >> 8;
    int c  = k & 255;
    float f = (o < 27) ? w[o * KTOT + c * 9 + kk] : 0.0f;
    unsigned short hi = f2bf(f);
    wH[idx] = hi;
    wL[idx] = f2bf(f - bf2f(hi));
}

// ---------------------------------------------------------------------------
// Fused offset conv: M=32(27) x N=64px x K=2304, split-bf16 3-term.
// Grid 288 x 512 threads; waves 0-3 K-half0, waves 4-7 K-half1.
// ---------------------------------------------------------------------------
__global__ __launch_bounds__(512) void offconv_fused(const float* __restrict__ xt,
                                                     const unsigned short* __restrict__ AH,
                                                     const unsigned short* __restrict__ AL,
                                                     const float* __restrict__ bias,
                                                     float* __restrict__ om) {
    __shared__ __attribute__((aligned(16))) unsigned short AsH[2][32 * 72];
    __shared__ __attribute__((aligned(16))) unsigned short AsL[2][32 * 72];
    __shared__ __attribute__((aligned(16))) unsigned short BsH[2][64 * 72];
    __shared__ __attribute__((aligned(16))) unsigned short BsL[2][64 * 72];

    const int tid  = threadIdx.x;
    const int kg   = tid >> 8;              // K-half
    const int tl   = tid & 255;             // local id within K-group
    const int lane = tid & 63;
    const int wq   = (tid >> 6) & 3;        // wave-quad within K-group
    const int quad = lane >> 4, l16 = lane & 15;
    const int g    = blockIdx.x;            // 288
    const int nb   = (g & 7) * 36 + (g >> 3);
    const int n0   = nb * 64;
    const int b    = n0 / PXB;
    const int hw0  = n0 - b * PXB;

    f32x4 acc[2];
#pragma unroll
    for (int mt = 0; mt < 2; ++mt) acc[mt] = (f32x4)0.0f;

    const int arow = tl >> 3, akg = tl & 7;

    for (int it = 0; it < 18; ++it) {
        const int kt = kg * 18 + it;
        const int kk = kt >> 2, c0 = (kt & 3) * 64;
        const int dy = kk / 3 - 1, dx = kk - (kk / 3) * 3 - 1;
        __syncthreads();
        {   // stage A (32 rows x 64 k)
            size_t ai = (size_t)arow * KTOT + kt * 64 + akg * 8;
            *(uint4*)&AsH[kg][arow * 72 + akg * 8] = *(const uint4*)&AH[ai];
            *(uint4*)&AsL[kg][arow * 72 + akg * 8] = *(const uint4*)&AL[ai];
        }
        // stage B (64 px x 64 c): 2 tasks/thread per K-group
#pragma unroll
        for (int i = 0; i < 2; ++i) {
            int task = i * 256 + tl;
            int px = task >> 3, cg = task & 7;
            int hw = hw0 + px;
            int h = hw / 96, w = hw - h * 96;
            int y = h + dy, x = w + dx;
            bool valid = ((unsigned)y < 96u) && ((unsigned)x < 96u);
            float4 v0 = make_float4(0.f, 0.f, 0.f, 0.f), v1 = v0;
            if (valid) {
                const float* p = xt + ((size_t)b * PXB + y * 96 + x) * 256 + c0 + cg * 8;
                v0 = *(const float4*)p;
                v1 = *(const float4*)(p + 4);
            }
            float vals[8] = {v0.x, v0.y, v0.z, v0.w, v1.x, v1.y, v1.z, v1.w};
            unsigned short hi[8], lo[8];
#pragma unroll
            for (int j = 0; j < 8; ++j) {
                hi[j] = f2bf(vals[j]);
                lo[j] = f2bf(vals[j] - bf2f(hi[j]));
            }
            *(uint4*)&BsH[kg][px * 72 + cg * 8] = *(uint4*)hi;
            *(uint4*)&BsL[kg][px * 72 + cg * 8] = *(uint4*)lo;
        }
        __syncthreads();
#pragma unroll
        for (int ks = 0; ks < 2; ++ks) {
            bf16x8 ah[2], al[2], bh, bl;
#pragma unroll
            for (int mt = 0; mt < 2; ++mt) {
                ah[mt] = *(const bf16x8*)&AsH[kg][(mt * 16 + l16) * 72 + ks * 32 + quad * 8];
                al[mt] = *(const bf16x8*)&AsL[kg][(mt * 16 + l16) * 72 + ks * 32 + quad * 8];
            }
            bh = *(const bf16x8*)&BsH[kg][(wq * 16 + l16) * 72 + ks * 32 + quad * 8];
            bl = *(const bf16x8*)&BsL[kg][(wq * 16 + l16) * 72 + ks * 32 + quad * 8];
#pragma unroll
            for (int mt = 0; mt < 2; ++mt) {
                acc[mt] = __builtin_amdgcn_mfma_f32_16x16x32_bf16(ah[mt], bh, acc[mt], 0, 0, 0);
                acc[mt] = __builtin_amdgcn_mfma_f32_16x16x32_bf16(ah[mt], bl, acc[mt], 0, 0, 0);
                acc[mt] = __builtin_amdgcn_mfma_f32_16x16x32_bf16(al[mt], bh, acc[mt], 0, 0, 0);
            }
        }
    }

    // ---- in-block split-K reduction: kg1 publishes, kg0 adds + stores ----
    float* red = (float*)BsH;   // 8 KB needed, 18 KB available
    __syncthreads();
    if (kg == 1) {
#pragma unroll
        for (int mt = 0; mt < 2; ++mt)
#pragma unroll
            for (int r = 0; r < 4; ++r)
                red[wq * 512 + mt * 256 + quad * 64 + r * 16 + l16] = acc[mt][r];
    }
    __syncthreads();
    if (kg == 0) {
#pragma unroll
        for (int mt = 0; mt < 2; ++mt)
#pragma unroll
            for (int r = 0; r < 4; ++r) {
                float v = acc[mt][r] + red[wq * 512 + mt * 256 + quad * 64 + r * 16 + l16];
                int m = mt * 16 + quad * 4 + r;
                int n = wq * 16 + l16;
                if (m < 27)
                    om[(size_t)(b * 27 + m) * PXB + hw0 + n] = v + bias[m];
            }
    }
}

// ---------------------------------------------------------------------------
// Fused deformable conv: tile 128m x 64n, K=2304, grid 576 x 512 threads.
// Waves 0-3 K-half0, waves 4-7 K-half1 (R8 pipelined loop per K-group);
// LDS split-K reduction; R7 epilogues (staging reuses Bs).
// ---------------------------------------------------------------------------
__global__ __launch_bounds__(512) void dfconv_fused(const float* __restrict__ xt,
                                                    const float* __restrict__ om,
                                                    const unsigned short* __restrict__ A,
                                                    float* __restrict__ out,
                                                    int out_mode) {
    __shared__ __attribute__((aligned(16))) unsigned short Bs[2][2][64 * 72]; // [kg][buf]
    __shared__ __attribute__((aligned(16))) unsigned short goff[576 * 4];
    __shared__ __attribute__((aligned(16))) float gwt[576 * 4];

    const int tid  = threadIdx.x;
    const int kg   = tid >> 8;
    const int tl   = tid & 255;
    const int lane = tid & 63;
    const int wq   = (tid >> 6) & 3;
    const int quad = lane >> 4, l16 = lane & 15;
    const int wn   = wq & 1, wm = wq >> 1;
    // XCD swizzle: g%8 = xcd; s = g/8; nb = xcd*36 + s/2; m-half = s%2.
    const int g    = blockIdx.x;            // 576
    const int s    = g >> 3;
    const int nb   = (g & 7) * 36 + (s >> 1);
    const int m0   = (s & 1) * 128;
    const int n0   = nb * 64;
    const int b    = n0 / PXB;
    const int hw0  = n0 - b * PXB;

    // ---- geometry: 64 px x 9 taps (all 512 threads) ----
    for (int task = tid; task < 576; task += 512) {
        int px = task / 9;
        int kk = task - px * 9;
        int hw = hw0 + px;
        int h = hw / 96, w = hw - h * 96;
        const float* omp = om + (size_t)b * 27 * PXB + hw;
        float dy = omp[(size_t)(2 * kk) * PXB];
        float dx = omp[(size_t)(2 * kk + 1) * PXB];
        float mv = omp[(size_t)(18 + kk) * PXB];
        float mk = 1.0f / (1.0f + __expf(-mv));

        float ys = (float)(h + (kk / 3) - 1) + dy;
        float xs = (float)(w + (kk - (kk / 3) * 3) - 1) + dx;
        float fy = floorf(ys), fx = floorf(xs);
        int iy = (int)fy, ix = (int)fx;
        float wy1 = ys - fy, wx1 = xs - fx;
        float wy0 = 1.0f - wy1, wx0 = 1.0f - wx1;
        bool yv0 = (unsigned)iy < 96u, yv1 = (unsigned)(iy + 1) < 96u;
        bool xv0 = (unsigned)ix < 96u, xv1 = (unsigned)(ix + 1) < 96u;
        int y0 = min(max(iy, 0), 95),     y1 = min(max(iy + 1, 0), 95);
        int x0 = min(max(ix, 0), 95),     x1 = min(max(ix + 1, 0), 95);
        int gg = task * 4;
        goff[gg + 0] = (unsigned short)(y0 * 96 + x0);
        goff[gg + 1] = (unsigned short)(y0 * 96 + x1);
        goff[gg + 2] = (unsigned short)(y1 * 96 + x0);
        goff[gg + 3] = (unsigned short)(y1 * 96 + x1);
        gwt[gg + 0] = (yv0 && xv0) ? mk * wy0 * wx0 : 0.0f;
        gwt[gg + 1] = (yv0 && xv1) ? mk * wy0 * wx1 : 0.0f;
        gwt[gg + 2] = (yv1 && xv0) ? mk * wy1 * wx0 : 0.0f;
        gwt[gg + 3] = (yv1 && xv1) ? mk * wy1 * wx1 : 0.0f;
    }

    f32x4 acc[4][2];
#pragma unroll
    for (int mt = 0; mt < 4; ++mt)
#pragma unroll
        for (int nt = 0; nt < 2; ++nt) acc[mt][nt] = (f32x4)0.0f;

    __syncthreads();   // geometry ready

    const int gpx = tl >> 3, gcg = tl & 7;
    const float* xbase = xt + (size_t)b * PXB * 256 + gcg * 8;
    const unsigned short* Arow = A + (size_t)(m0 + wm * 64 + l16) * KTOT + quad * 8;
    const int kt0 = kg * 18;

    // ---- prologue: gather panel it=0 -> Bs[kg][0] ----
    {
        const int kkp = kt0 >> 2, c0p = (kt0 & 3) * 64;
#pragma unroll
        for (int i = 0; i < 2; ++i) {
            int px = gpx + i * 32;
            int gg = (px * 9 + kkp) * 4;
            ushort4 o4 = *(const ushort4*)&goff[gg];
            float4  wt = *(const float4*)&gwt[gg];
            const float* cb = xbase + c0p;
            const float* p0 = cb + (size_t)o4.x * 256;
            const float* p1 = cb + (size_t)o4.y * 256;
            const float* p2 = cb + (size_t)o4.z * 256;
            const float* p3 = cb + (size_t)o4.w * 256;
            float4 q0 = *(const float4*)p0, q1 = *(const float4*)p1;
            float4 q2 = *(const float4*)p2, q3 = *(const float4*)p3;
            float4 r0 = *(const float4*)(p0 + 4), r1 = *(const float4*)(p1 + 4);
            float4 r2 = *(const float4*)(p2 + 4), r3 = *(const float4*)(p3 + 4);
            unsigned short res[8];
            res[0] = f2bf(wt.x*q0.x + wt.y*q1.x + wt.z*q2.x + wt.w*q3.x);
            res[1] = f2bf(wt.x*q0.y + wt.y*q1.y + wt.z*q2.y + wt.w*q3.y);
            res[2] = f2bf(wt.x*q0.z + wt.y*q1.z + wt.z*q2.z + wt.w*q3.z);
            res[3] = f2bf(wt.x*q0.w + wt.y*q1.w + wt.z*q2.w + wt.w*q3.w);
            res[4] = f2bf(wt.x*r0.x + wt.y*r1.x + wt.z*r2.x + wt.w*r3.x);
            res[5] = f2bf(wt.x*r0.y + wt.y*r1.y + wt.z*r2.y + wt.w*r3.y);
            res[6] = f2bf(wt.x*r0.z + wt.y*r1.z + wt.z*r2.z + wt.w*r3.z);
            res[7] = f2bf(wt.x*r0.w + wt.y*r1.w + wt.z*r2.w + wt.w*r3.w);
            *(uint4*)&Bs[kg][0][px * 72 + gcg * 8] = *(uint4*)res;
        }
    }
    __syncthreads();

    for (int it = 0; it < 18; ++it) {
        const int kt = kt0 + it;
        const int cur = it & 1;
        // (1) A fragments for kt
        bf16x8 af[2][4];
#pragma unroll
        for (int ks = 0; ks < 2; ++ks)
#pragma unroll
            for (int mt = 0; mt < 4; ++mt)
                af[ks][mt] = *(const bf16x8*)(Arow + (size_t)(mt * 16) * KTOT + kt * 64 + ks * 32);

        // (2) issue gather loads for it+1
        float4 gq[2][8]; float4 gw[2];
        if (it < 17) {
            const int kkn = (kt + 1) >> 2;
            const int c0n = ((kt + 1) & 3) * 64;
#pragma unroll
            for (int i = 0; i < 2; ++i) {
                int px = gpx + i * 32;
                int gg = (px * 9 + kkn) * 4;
                ushort4 o4 = *(const ushort4*)&goff[gg];
                gw[i] = *(const float4*)&gwt[gg];
                const float* cb = xbase + c0n;
                const float* p0 = cb + (size_t)o4.x * 256;
                const float* p1 = cb + (size_t)o4.y * 256;
                const float* p2 = cb + (size_t)o4.z * 256;
                const float* p3 = cb + (size_t)o4.w * 256;
                gq[i][0] = *(const float4*)p0;       gq[i][1] = *(const float4*)p1;
                gq[i][2] = *(const float4*)p2;       gq[i][3] = *(const float4*)p3;
                gq[i][4] = *(const float4*)(p0 + 4); gq[i][5] = *(const float4*)(p1 + 4);
                gq[i][6] = *(const float4*)(p2 + 4); gq[i][7] = *(const float4*)(p3 + 4);
            }
        }

        // (3) MFMA phase
#pragma unroll
        for (int ks = 0; ks < 2; ++ks) {
            bf16x8 bfr[2];
#pragma unroll
            for (int nt = 0; nt < 2; ++nt)
                bfr[nt] = *(const bf16x8*)&Bs[kg][cur][(wn * 32 + nt * 16 + l16) * 72 + ks * 32 + quad * 8];
#pragma unroll
            for (int mt = 0; mt < 4; ++mt)
#pragma unroll
                for (int nt = 0; nt < 2; ++nt)
                    acc[mt][nt] = __builtin_amdgcn_mfma_f32_16x16x32_bf16(
                        af[ks][mt], bfr[nt], acc[mt][nt], 0, 0, 0);
        }

        // (4) convert + write next panel
        if (it < 17) {
#pragma unroll
            for (int i = 0; i < 2; ++i) {
                int px = gpx + i * 32;
                float4 wt = gw[i];
                unsigned short res[8];
                res[0] = f2bf(wt.x*gq[i][0].x + wt.y*gq[i][1].x + wt.z*gq[i][2].x + wt.w*gq[i][3].x);
                res[1] = f2bf(wt.x*gq[i][0].y + wt.y*gq[i][1].y + wt.z*gq[i][2].y + wt.w*gq[i][3].y);
                res[2] = f2bf(wt.x*gq[i][0].z + wt.y*gq[i][1].z + wt.z*gq[i][2].z + wt.w*gq[i][3].z);
                res[3] = f2bf(wt.x*gq[i][0].w + wt.y*gq[i][1].w + wt.z*gq[i][2].w + wt.w*gq[i][3].w);
                res[4] = f2bf(wt.x*gq[i][4].x + wt.y*gq[i][5].x + wt.z*gq[i][6].x + wt.w*gq[i][7].x);
                res[5] = f2bf(wt.x*gq[i][4].y + wt.y*gq[i][5].y + wt.z*gq[i][6].y + wt.w*gq[i][7].y);
                res[6] = f2bf(wt.x*gq[i][4].z + wt.y*gq[i][5].z + wt.z*gq[i][6].z + wt.w*gq[i][7].z);
                res[7] = f2bf(wt.x*gq[i][4].w + wt.y*gq[i][5].w + wt.z*gq[i][6].w + wt.w*gq[i][7].w);
                *(uint4*)&Bs[kg][cur ^ 1][px * 72 + gcg * 8] = *(uint4*)res;
            }
        }
        __syncthreads();
    }

    // ---- in-block split-K reduction: kg1 publishes, kg0 adds ----
    float* red = (float*)Bs;    // 32 KB needed, 36 KB available
    __syncthreads();
    if (kg == 1) {
#pragma unroll
        for (int mt = 0; mt < 4; ++mt)
#pragma unroll
            for (int nt = 0; nt < 2; ++nt)
#pragma unroll
                for (int r = 0; r < 4; ++r)
                    red[wq * 2048 + mt * 512 + nt * 256 + quad * 64 + r * 16 + l16] = acc[mt][nt][r];
    }
    __syncthreads();
    if (kg == 0) {
#pragma unroll
        for (int mt = 0; mt < 4; ++mt)
#pragma unroll
            for (int nt = 0; nt < 2; ++nt)
#pragma unroll
                for (int r = 0; r < 4; ++r)
                    acc[mt][nt][r] += red[wq * 2048 + mt * 512 + nt * 256 + quad * 64 + r * 16 + l16];
    }

    // ---- epilogues (kg0 holds the sum; staging reuses Bs) ----
    float* tile = (float*)Bs;
    if (out_mode == 0) {
        // NCHW out[b][m][hw]: 2 passes of 64 m x 64 n; tile stride 68.
#pragma unroll
        for (int pass = 0; pass < 2; ++pass) {
            __syncthreads();
            if (kg == 0 && wm == pass) {
#pragma unroll
                for (int mt = 0; mt < 4; ++mt)
#pragma unroll
                    for (int nt = 0; nt < 2; ++nt)
#pragma unroll
                        for (int r = 0; r < 4; ++r) {
                            int ml = mt * 16 + quad * 4 + r;      // 0..63
                            int n  = wn * 32 + nt * 16 + l16;     // 0..63
                            tile[ml * 68 + n] = fmaxf(acc[mt][nt][r], 0.0f);
                        }
            }
            __syncthreads();
#pragma unroll
            for (int j = 0; j < 2; ++j) {
                int idx = j * 512 + tid;          // 1024 float4s = 64m x 16q
                int row = idx >> 4, q = idx & 15;
                int m = m0 + pass * 64 + row;
                *(float4*)&out[(size_t)(b * 256 + m) * PXB + hw0 + q * 4] =
                    *(const float4*)&tile[row * 68 + q * 4];
            }
        }
    } else {
        // NHWC out[b][hw][m0+..]: 2 passes of 32 px x 128 ch; tile stride 132.
#pragma unroll
        for (int pass = 0; pass < 2; ++pass) {
            __syncthreads();
            if (kg == 0 && wn == pass) {
#pragma unroll
                for (int mt = 0; mt < 4; ++mt)
#pragma unroll
                    for (int nt = 0; nt < 2; ++nt) {
                        int row = nt * 16 + l16;                  // 0..31
                        int col = wm * 64 + mt * 16 + quad * 4;   // 0..127
                        f32x4 v = acc[mt][nt];
                        v[0] = fmaxf(v[0], 0.f); v[1] = fmaxf(v[1], 0.f);
                        v[2] = fmaxf(v[2], 0.f); v[3] = fmaxf(v[3], 0.f);
                        *(f32x4*)&tile[row * 132 + col] = v;
                    }
            }
            __syncthreads();
#pragma unroll
            for (int j = 0; j < 2; ++j) {
                int idx = j * 512 + tid;          // 1024 float4s = 32px x 32
                int pxl = idx >> 5, ln = idx & 31;
                *(float4*)&out[((size_t)b * PXB + hw0 + pass * 32 + pxl) * 256 + m0 + ln * 4] =
                    *(const float4*)&tile[pxl * 132 + ln * 4];
            }
        }
    }
}

// ---------------------------------------------------------------------------
extern "C" void kernel_launch(void* const* d_in, const int* in_sizes, int n_in,
                              void* d_out, int out_size, void* d_ws, size_t ws_size,
                              hipStream_t stream) {
    const float* x     = (const float*)d_in[0];
    const float* woff0 = (const float*)d_in[1];
    const float* boff0 = (const float*)d_in[2];
    const float* w0    = (const float*)d_in[3];
    const float* woff1 = (const float*)d_in[4];
    const float* boff1 = (const float*)d_in[5];
    const float* w1    = (const float*)d_in[6];
    float* out = (float*)d_out;

    char* p = (char*)d_ws;
    float* om  = (float*)p;  p += (size_t)2 * 27 * PXB * 4;               // 2.0 MB
    float* xt  = (float*)p;  p += (size_t)2 * 256 * PXB * 4;              // 18.9 MB
    float* h1t = (float*)p;  p += (size_t)2 * 256 * PXB * 4;              // 18.9 MB
    unsigned short* wA0 = (unsigned short*)p; p += (size_t)256 * KTOT * 2;
    unsigned short* wA1 = (unsigned short*)p; p += (size_t)256 * KTOT * 2;
    unsigned short* wH0 = (unsigned short*)p; p += (size_t)32 * KTOT * 2;
    unsigned short* wL0 = (unsigned short*)p; p += (size_t)32 * KTOT * 2;
    unsigned short* wH1 = (unsigned short*)p; p += (size_t)32 * KTOT * 2;
    unsigned short* wL1 = (unsigned short*)p; p += (size_t)32 * KTOT * 2;

    hipLaunchKernelGGL(transpose_kernel, dim3(PXB / 64, 4, 2), dim3(256), 0, stream, x, xt);
    hipLaunchKernelGGL(prep_w_kernel, dim3(256 * KTOT / 256), dim3(256), 0, stream, w0, wA0);
    hipLaunchKernelGGL(prep_w_kernel, dim3(256 * KTOT / 256), dim3(256), 0, stream, w1, wA1);
    hipLaunchKernelGGL(prep_woff_kernel, dim3(32 * KTOT / 256), dim3(256), 0, stream, woff0, wH0, wL0);
    hipLaunchKernelGGL(prep_woff_kernel, dim3(32 * KTOT / 256), dim3(256), 0, stream, woff1, wH1, wL1);

    // Layer 0: x(NHWC) -> h1t(NHWC)
    hipLaunchKernelGGL(offconv_fused, dim3(288), dim3(512), 0, stream, xt, wH0, wL0, boff0, om);
    hipLaunchKernelGGL(dfconv_fused, dim3(576), dim3(512), 0, stream, xt, om, wA0, h1t, 1);

    // Layer 1: h1t(NHWC) -> out(NCHW)
    hipLaunchKernelGGL(offconv_fused, dim3(288), dim3(512), 0, stream, h1t, wH1, wL1, boff1, om);
    hipLaunchKernelGGL(dfconv_fused, dim3(576), dim3(512), 0, stream, h1t, om, wA1, out, 0);
}

// Round 10
// 428.253 us; speedup vs baseline: 4.2725x; 1.1485x over previous
//
#include <hip/hip_runtime.h>
#include <cstdint>
#include <cstddef>

// DCNv2 x2 (B=2, C=O=256, H=W=96, k=3), fully fused per layer.
// R10: dfconv rebuilt as PRODUCER/CONSUMER wave specialization:
//   waves 0-3 gather+convert into a 4-deep LDS ring (no __syncthreads in the
//   K-loop), waves 4-7 (one per 64-row m-quarter) run MFMA off the ring with
//   A-fragments direct from L2-hot global. Sync: monotonic LDS counters
//   ready[4]/done[4] + __threadfence_block. Tile M=256 x N=32 (removes the
//   2x gather duplication of R9). offconv/transpose/preps = R9 verbatim.
// k' = kk*256 + c. Activations NHWC. XCD swizzle: blockIdx%8 = XCD.

#define KTOT 2304
#define PXB  9216

typedef __attribute__((ext_vector_type(8))) short bf16x8;
typedef __attribute__((ext_vector_type(4))) float f32x4;

static __device__ __forceinline__ unsigned short f2bf(float f) {
    union { float f; unsigned int u; } v; v.f = f;
    unsigned int r = (v.u + 0x7FFFu + ((v.u >> 16) & 1u)) >> 16;
    return (unsigned short)r;
}
static __device__ __forceinline__ float bf2f(unsigned short h) {
    union { unsigned int u; float f; } v; v.u = ((unsigned int)h) << 16;
    return v.f;
}

// ---------------------------------------------------------------------------
// NCHW -> NHWC transpose
// ---------------------------------------------------------------------------
__global__ __launch_bounds__(256) void transpose_kernel(const float* __restrict__ in,
                                                        float* __restrict__ outT) {
    __shared__ float tile[64][65];
    const int hw0 = blockIdx.x * 64;
    const int c0  = blockIdx.y * 64;
    const int b   = blockIdx.z;
    const int lx  = threadIdx.x & 63;
    const int ly  = threadIdx.x >> 6;
#pragma unroll
    for (int i = 0; i < 16; ++i) {
        int cl = ly + i * 4;
        tile[cl][lx] = in[(size_t)(b * 256 + c0 + cl) * PXB + hw0 + lx];
    }
    __syncthreads();
#pragma unroll
    for (int i = 0; i < 16; ++i) {
        int hwl = ly + i * 4;
        outT[((size_t)b * PXB + hw0 + hwl) * 256 + c0 + lx] = tile[lx][hwl];
    }
}

// ---------------------------------------------------------------------------
// Main weight prep: w[o][c][kk] fp32 -> wA[o][k'=kk*256+c] bf16
// ---------------------------------------------------------------------------
__global__ __launch_bounds__(256) void prep_w_kernel(const float* __restrict__ w,
                                                     unsigned short* __restrict__ wA) {
    int idx = blockIdx.x * 256 + threadIdx.x;   // 256*2304
    int o = idx / KTOT;
    int k = idx - o * KTOT;
    int kk = k >> 8;
    int c  = k & 255;
    wA[idx] = f2bf(w[o * KTOT + c * 9 + kk]);
}

// ---------------------------------------------------------------------------
// Offset weight prep (split): rows 27..32 zero. hi = bf16(w), lo = bf16(w-hi).
// ---------------------------------------------------------------------------
__global__ __launch_bounds__(256) void prep_woff_kernel(const float* __restrict__ w,
                                                        unsigned short* __restrict__ wH,
                                                        unsigned short* __restrict__ wL) {
    int idx = blockIdx.x * 256 + threadIdx.x;   // 32*2304
    int o = idx / KTOT;
    int k = idx - o * KTOT;
    int kk = k >> 8;
    int c  = k & 255;
    float f = (o < 27) ? w[o * KTOT + c * 9 + kk] : 0.0f;
    unsigned short hi = f2bf(f);
    wH[idx] = hi;
    wL[idx] = f2bf(f - bf2f(hi));
}

// ---------------------------------------------------------------------------
// Fused offset conv: M=32(27) x N=64px x K=2304, split-bf16 3-term.
// Grid 288 x 512 threads; waves 0-3 K-half0, waves 4-7 K-half1. (R9 verbatim)
// ---------------------------------------------------------------------------
__global__ __launch_bounds__(512) void offconv_fused(const float* __restrict__ xt,
                                                     const unsigned short* __restrict__ AH,
                                                     const unsigned short* __restrict__ AL,
                                                     const float* __restrict__ bias,
                                                     float* __restrict__ om) {
    __shared__ __attribute__((aligned(16))) unsigned short AsH[2][32 * 72];
    __shared__ __attribute__((aligned(16))) unsigned short AsL[2][32 * 72];
    __shared__ __attribute__((aligned(16))) unsigned short BsH[2][64 * 72];
    __shared__ __attribute__((aligned(16))) unsigned short BsL[2][64 * 72];

    const int tid  = threadIdx.x;
    const int kg   = tid >> 8;
    const int tl   = tid & 255;
    const int lane = tid & 63;
    const int wq   = (tid >> 6) & 3;
    const int quad = lane >> 4, l16 = lane & 15;
    const int g    = blockIdx.x;            // 288
    const int nb   = (g & 7) * 36 + (g >> 3);
    const int n0   = nb * 64;
    const int b    = n0 / PXB;
    const int hw0  = n0 - b * PXB;

    f32x4 acc[2];
#pragma unroll
    for (int mt = 0; mt < 2; ++mt) acc[mt] = (f32x4)0.0f;

    const int arow = tl >> 3, akg = tl & 7;

    for (int it = 0; it < 18; ++it) {
        const int kt = kg * 18 + it;
        const int kk = kt >> 2, c0 = (kt & 3) * 64;
        const int dy = kk / 3 - 1, dx = kk - (kk / 3) * 3 - 1;
        __syncthreads();
        {   // stage A (32 rows x 64 k)
            size_t ai = (size_t)arow * KTOT + kt * 64 + akg * 8;
            *(uint4*)&AsH[kg][arow * 72 + akg * 8] = *(const uint4*)&AH[ai];
            *(uint4*)&AsL[kg][arow * 72 + akg * 8] = *(const uint4*)&AL[ai];
        }
        // stage B (64 px x 64 c): 2 tasks/thread per K-group
#pragma unroll
        for (int i = 0; i < 2; ++i) {
            int task = i * 256 + tl;
            int px = task >> 3, cg = task & 7;
            int hw = hw0 + px;
            int h = hw / 96, w = hw - h * 96;
            int y = h + dy, x = w + dx;
            bool valid = ((unsigned)y < 96u) && ((unsigned)x < 96u);
            float4 v0 = make_float4(0.f, 0.f, 0.f, 0.f), v1 = v0;
            if (valid) {
                const float* p = xt + ((size_t)b * PXB + y * 96 + x) * 256 + c0 + cg * 8;
                v0 = *(const float4*)p;
                v1 = *(const float4*)(p + 4);
            }
            float vals[8] = {v0.x, v0.y, v0.z, v0.w, v1.x, v1.y, v1.z, v1.w};
            unsigned short hi[8], lo[8];
#pragma unroll
            for (int j = 0; j < 8; ++j) {
                hi[j] = f2bf(vals[j]);
                lo[j] = f2bf(vals[j] - bf2f(hi[j]));
            }
            *(uint4*)&BsH[kg][px * 72 + cg * 8] = *(uint4*)hi;
            *(uint4*)&BsL[kg][px * 72 + cg * 8] = *(uint4*)lo;
        }
        __syncthreads();
#pragma unroll
        for (int ks = 0; ks < 2; ++ks) {
            bf16x8 ah[2], al[2], bh, bl;
#pragma unroll
            for (int mt = 0; mt < 2; ++mt) {
                ah[mt] = *(const bf16x8*)&AsH[kg][(mt * 16 + l16) * 72 + ks * 32 + quad * 8];
                al[mt] = *(const bf16x8*)&AsL[kg][(mt * 16 + l16) * 72 + ks * 32 + quad * 8];
            }
            bh = *(const bf16x8*)&BsH[kg][(wq * 16 + l16) * 72 + ks * 32 + quad * 8];
            bl = *(const bf16x8*)&BsL[kg][(wq * 16 + l16) * 72 + ks * 32 + quad * 8];
#pragma unroll
            for (int mt = 0; mt < 2; ++mt) {
                acc[mt] = __builtin_amdgcn_mfma_f32_16x16x32_bf16(ah[mt], bh, acc[mt], 0, 0, 0);
                acc[mt] = __builtin_amdgcn_mfma_f32_16x16x32_bf16(ah[mt], bl, acc[mt], 0, 0, 0);
                acc[mt] = __builtin_amdgcn_mfma_f32_16x16x32_bf16(al[mt], bh, acc[mt], 0, 0, 0);
            }
        }
    }

    // ---- in-block split-K reduction: kg1 publishes, kg0 adds + stores ----
    float* red = (float*)BsH;
    __syncthreads();
    if (kg == 1) {
#pragma unroll
        for (int mt = 0; mt < 2; ++mt)
#pragma unroll
            for (int r = 0; r < 4; ++r)
                red[wq * 512 + mt * 256 + quad * 64 + r * 16 + l16] = acc[mt][r];
    }
    __syncthreads();
    if (kg == 0) {
#pragma unroll
        for (int mt = 0; mt < 2; ++mt)
#pragma unroll
            for (int r = 0; r < 4; ++r) {
                float v = acc[mt][r] + red[wq * 512 + mt * 256 + quad * 64 + r * 16 + l16];
                int m = mt * 16 + quad * 4 + r;
                int n = wq * 16 + l16;
                if (m < 27)
                    om[(size_t)(b * 27 + m) * PXB + hw0 + n] = v + bias[m];
            }
    }
}

// ---------------------------------------------------------------------------
// Fused deformable conv, producer/consumer: M=256 x N=32px, K=2304.
// Grid 576 x 512 thr. Waves 0-3 produce B panels into a 4-deep LDS ring;
// waves 4-7 (one per 64-row m-quarter) consume with MFMA.
// ---------------------------------------------------------------------------
__global__ __launch_bounds__(512) void dfconv_fused(const float* __restrict__ xt,
                                                    const float* __restrict__ om,
                                                    const unsigned short* __restrict__ A,
                                                    float* __restrict__ out,
                                                    int out_mode) {
    __shared__ __attribute__((aligned(16))) unsigned short Bs[4][32 * 72]; // ring, 18.4 KB
    __shared__ __attribute__((aligned(16))) unsigned short goff[288 * 4];
    __shared__ __attribute__((aligned(16))) float gwt[288 * 4];
    __shared__ __attribute__((aligned(16))) float tileS[4608];   // 18 KB epilogue
    __shared__ int ready[4];   // monotonic: producers inc once per (stage,round)
    __shared__ int done[4];    // monotonic: consumers inc once per (stage,round)

    const int tid  = threadIdx.x;
    const int wv   = tid >> 6;
    const int lane = tid & 63;
    const int quad = lane >> 4, l16 = lane & 15;
    // XCD swizzle: g%8 = xcd owns n-blocks [xcd*72, xcd*72+72)
    const int g    = blockIdx.x;            // 576
    const int nb   = (g & 7) * 72 + (g >> 3);
    const int n0   = nb * 32;
    const int b    = n0 / PXB;
    const int hw0  = n0 - b * PXB;

    if (tid < 4) { ready[tid] = 0; done[tid] = 0; }

    // ---- geometry: 32 px x 9 taps ----
    if (tid < 288) {
        int task = tid;
        int px = task / 9;
        int kk = task - px * 9;
        int hw = hw0 + px;
        int h = hw / 96, w = hw - h * 96;
        const float* omp = om + (size_t)b * 27 * PXB + hw;
        float dyv = omp[(size_t)(2 * kk) * PXB];
        float dxv = omp[(size_t)(2 * kk + 1) * PXB];
        float mv  = omp[(size_t)(18 + kk) * PXB];
        float mk  = 1.0f / (1.0f + __expf(-mv));

        float ys = (float)(h + (kk / 3) - 1) + dyv;
        float xs = (float)(w + (kk - (kk / 3) * 3) - 1) + dxv;
        float fy = floorf(ys), fx = floorf(xs);
        int iy = (int)fy, ix = (int)fx;
        float wy1 = ys - fy, wx1 = xs - fx;
        float wy0 = 1.0f - wy1, wx0 = 1.0f - wx1;
        bool yv0 = (unsigned)iy < 96u, yv1 = (unsigned)(iy + 1) < 96u;
        bool xv0 = (unsigned)ix < 96u, xv1 = (unsigned)(ix + 1) < 96u;
        int y0 = min(max(iy, 0), 95),     y1 = min(max(iy + 1, 0), 95);
        int x0 = min(max(ix, 0), 95),     x1 = min(max(ix + 1, 0), 95);
        int gg = task * 4;
        goff[gg + 0] = (unsigned short)(y0 * 96 + x0);
        goff[gg + 1] = (unsigned short)(y0 * 96 + x1);
        goff[gg + 2] = (unsigned short)(y1 * 96 + x0);
        goff[gg + 3] = (unsigned short)(y1 * 96 + x1);
        gwt[gg + 0] = (yv0 && xv0) ? mk * wy0 * wx0 : 0.0f;
        gwt[gg + 1] = (yv0 && xv1) ? mk * wy0 * wx1 : 0.0f;
        gwt[gg + 2] = (yv1 && xv0) ? mk * wy1 * wx0 : 0.0f;
        gwt[gg + 3] = (yv1 && xv1) ? mk * wy1 * wx1 : 0.0f;
    }
    __syncthreads();   // geometry + flags visible to all waves

    volatile int* vready = ready;
    volatile int* vdone  = done;

    f32x4 acc[4][2];
#pragma unroll
    for (int mt = 0; mt < 4; ++mt) { acc[mt][0] = (f32x4)0.0f; acc[mt][1] = (f32x4)0.0f; }

    if (wv < 4) {
        // ================= PRODUCERS (waves 0-3) =================
        const int pl = wv * 64 + lane;      // 0..255: cell id
        const int px = pl >> 3, cg = pl & 7;
        const float* xbase = xt + (size_t)b * PXB * 256 + cg * 8;

        for (int kt = 0; kt < 36; ++kt) {
            const int st = kt & 3, rr = kt >> 2;
            const int tap = kt >> 2, c0 = (kt & 3) * 64;
            // geometry + issue loads first (latency hides inside the poll)
            int gg = (px * 9 + tap) * 4;
            ushort4 o4 = *(const ushort4*)&goff[gg];
            float4  wt = *(const float4*)&gwt[gg];
            const float* cb = xbase + c0;
            const float* p0 = cb + (size_t)o4.x * 256;
            const float* p1 = cb + (size_t)o4.y * 256;
            const float* p2 = cb + (size_t)o4.z * 256;
            const float* p3 = cb + (size_t)o4.w * 256;
            float4 q0 = *(const float4*)p0,       q1 = *(const float4*)p1;
            float4 q2 = *(const float4*)p2,       q3 = *(const float4*)p3;
            float4 r0 = *(const float4*)(p0 + 4), r1 = *(const float4*)(p1 + 4);
            float4 r2 = *(const float4*)(p2 + 4), r3 = *(const float4*)(p3 + 4);
            // wait until consumers finished with this ring slot (round rr-1)
            const int tgt = 4 * rr;
            while (vdone[st] < tgt) __builtin_amdgcn_s_sleep(1);
            // convert + write panel
            unsigned short res[8];
            res[0] = f2bf(wt.x*q0.x + wt.y*q1.x + wt.z*q2.x + wt.w*q3.x);
            res[1] = f2bf(wt.x*q0.y + wt.y*q1.y + wt.z*q2.y + wt.w*q3.y);
            res[2] = f2bf(wt.x*q0.z + wt.y*q1.z + wt.z*q2.z + wt.w*q3.z);
            res[3] = f2bf(wt.x*q0.w + wt.y*q1.w + wt.z*q2.w + wt.w*q3.w);
            res[4] = f2bf(wt.x*r0.x + wt.y*r1.x + wt.z*r2.x + wt.w*r3.x);
            res[5] = f2bf(wt.x*r0.y + wt.y*r1.y + wt.z*r2.y + wt.w*r3.y);
            res[6] = f2bf(wt.x*r0.z + wt.y*r1.z + wt.z*r2.z + wt.w*r3.z);
            res[7] = f2bf(wt.x*r0.w + wt.y*r1.w + wt.z*r2.w + wt.w*r3.w);
            *(uint4*)&Bs[st][px * 72 + cg * 8] = *(uint4*)res;
            __threadfence_block();           // drain ds_writes before signaling
            if (lane == 0) atomicAdd(&ready[st], 1);
        }
    } else {
        // ================= CONSUMERS (waves 4-7) =================
        const int mq = wv - 4;              // m-quarter
        const unsigned short* Arow = A + (size_t)(mq * 64 + l16) * KTOT + quad * 8;

        for (int kt = 0; kt < 36; ++kt) {
            const int st = kt & 3, rr = kt >> 2;
            // issue A-fragment loads first (overlap the ready-poll)
            bf16x8 af[2][4];
#pragma unroll
            for (int ks = 0; ks < 2; ++ks)
#pragma unroll
                for (int mt = 0; mt < 4; ++mt)
                    af[ks][mt] = *(const bf16x8*)(Arow + (size_t)(mt * 16) * KTOT + kt * 64 + ks * 32);
            // wait for all 4 producers to fill this slot for round rr
            const int tgt = 4 * (rr + 1);
            while (vready[st] < tgt) __builtin_amdgcn_s_sleep(1);
#pragma unroll
            for (int ks = 0; ks < 2; ++ks) {
                bf16x8 bfr[2];
#pragma unroll
                for (int nt = 0; nt < 2; ++nt)
                    bfr[nt] = *(const bf16x8*)&Bs[st][(nt * 16 + l16) * 72 + ks * 32 + quad * 8];
#pragma unroll
                for (int mt = 0; mt < 4; ++mt)
#pragma unroll
                    for (int nt = 0; nt < 2; ++nt)
                        acc[mt][nt] = __builtin_amdgcn_mfma_f32_16x16x32_bf16(
                            af[ks][mt], bfr[nt], acc[mt][nt], 0, 0, 0);
            }
            __threadfence_block();           // ds_reads complete before release
            if (lane == 0) atomicAdd(&done[st], 1);
        }
    }

    __syncthreads();   // join producers + consumers for the epilogue

    // ---- epilogues: LDS-staged contiguous stores (acc lives in waves 4-7) ----
    if (out_mode == 0) {
        // NCHW out[b][m][hw0..+31]: 2 passes of 128 m; tileS[128][36]
#pragma unroll
        for (int pass = 0; pass < 2; ++pass) {
            if (wv >= 4 && (wv - 4) >> 1 == pass) {
                int mqh = (wv - 4) & 1;     // m-quarter within this pass
#pragma unroll
                for (int mt = 0; mt < 4; ++mt)
#pragma unroll
                    for (int nt = 0; nt < 2; ++nt)
#pragma unroll
                        for (int r = 0; r < 4; ++r) {
                            int ml = mqh * 64 + mt * 16 + quad * 4 + r;   // 0..127
                            int n  = nt * 16 + l16;                        // 0..31
                            tileS[ml * 36 + n] = fmaxf(acc[mt][nt][r], 0.0f);
                        }
            }
            __syncthreads();
#pragma unroll
            for (int j = 0; j < 2; ++j) {
                int idx = j * 512 + tid;          // 1024 float4s = 128m x 8q
                int row = idx >> 3, q = idx & 7;
                int m = pass * 128 + row;
                *(float4*)&out[(size_t)(b * 256 + m) * PXB + hw0 + q * 4] =
                    *(const float4*)&tileS[row * 36 + q * 4];
            }
            __syncthreads();
        }
    } else {
        // NHWC out[b][hw][c]: 2 passes of 16 px; tileS[16][264]
#pragma unroll
        for (int pass = 0; pass < 2; ++pass) {
            if (wv >= 4) {
                int mq = wv - 4;
#pragma unroll
                for (int mt = 0; mt < 4; ++mt) {
                    f32x4 v = acc[mt][pass];
                    v[0] = fmaxf(v[0], 0.f); v[1] = fmaxf(v[1], 0.f);
                    v[2] = fmaxf(v[2], 0.f); v[3] = fmaxf(v[3], 0.f);
                    *(f32x4*)&tileS[l16 * 264 + mq * 64 + mt * 16 + quad * 4] = v;
                }
            }
            __syncthreads();
#pragma unroll
            for (int j = 0; j < 2; ++j) {
                int idx = j * 512 + tid;          // 1024 float4s = 16px x 64
                int pxl = idx >> 6, ln = idx & 63;
                *(float4*)&out[((size_t)b * PXB + hw0 + pass * 16 + pxl) * 256 + ln * 4] =
                    *(const float4*)&tileS[pxl * 264 + ln * 4];
            }
            __syncthreads();
        }
    }
}

// ---------------------------------------------------------------------------
extern "C" void kernel_launch(void* const* d_in, const int* in_sizes, int n_in,
                              void* d_out, int out_size, void* d_ws, size_t ws_size,
                              hipStream_t stream) {
    const float* x     = (const float*)d_in[0];
    const float* woff0 = (const float*)d_in[1];
    const float* boff0 = (const float*)d_in[2];
    const float* w0    = (const float*)d_in[3];
    const float* woff1 = (const float*)d_in[4];
    const float* boff1 = (const float*)d_in[5];
    const float* w1    = (const float*)d_in[6];
    float* out = (float*)d_out;

    char* p = (char*)d_ws;
    float* om  = (float*)p;  p += (size_t)2 * 27 * PXB * 4;               // 2.0 MB
    float* xt  = (float*)p;  p += (size_t)2 * 256 * PXB * 4;              // 18.9 MB
    float* h1t = (float*)p;  p += (size_t)2 * 256 * PXB * 4;              // 18.9 MB
    unsigned short* wA0 = (unsigned short*)p; p += (size_t)256 * KTOT * 2;
    unsigned short* wA1 = (unsigned short*)p; p += (size_t)256 * KTOT * 2;
    unsigned short* wH0 = (unsigned short*)p; p += (size_t)32 * KTOT * 2;
    unsigned short* wL0 = (unsigned short*)p; p += (size_t)32 * KTOT * 2;
    unsigned short* wH1 = (unsigned short*)p; p += (size_t)32 * KTOT * 2;
    unsigned short* wL1 = (unsigned short*)p; p += (size_t)32 * KTOT * 2;

    hipLaunchKernelGGL(transpose_kernel, dim3(PXB / 64, 4, 2), dim3(256), 0, stream, x, xt);
    hipLaunchKernelGGL(prep_w_kernel, dim3(256 * KTOT / 256), dim3(256), 0, stream, w0, wA0);
    hipLaunchKernelGGL(prep_w_kernel, dim3(256 * KTOT / 256), dim3(256), 0, stream, w1, wA1);
    hipLaunchKernelGGL(prep_woff_kernel, dim3(32 * KTOT / 256), dim3(256), 0, stream, woff0, wH0, wL0);
    hipLaunchKernelGGL(prep_woff_kernel, dim3(32 * KTOT / 256), dim3(256), 0, stream, woff1, wH1, wL1);

    // Layer 0: x(NHWC) -> h1t(NHWC)
    hipLaunchKernelGGL(offconv_fused, dim3(288), dim3(512), 0, stream, xt, wH0, wL0, boff0, om);
    hipLaunchKernelGGL(dfconv_fused, dim3(576), dim3(512), 0, stream, xt, om, wA0, h1t, 1);

    // Layer 1: h1t(NHWC) -> out(NCHW)
    hipLaunchKernelGGL(offconv_fused, dim3(288), dim3(512), 0, stream, h1t, wH1, wL1, boff1, om);
    hipLaunchKernelGGL(dfconv_fused, dim3(576), dim3(512), 0, stream, h1t, om, wA1, out, 0);
}

// Round 11
// 404.502 us; speedup vs baseline: 4.5234x; 1.0587x over previous
//
#include <hip/hip_runtime.h>
#include <cstdint>
#include <cstddef>

// DCNv2 x2 (B=2, C=O=256, H=W=96, k=3), fully fused per layer.
// R11: dfconv gather reads a bf16 NHWC activation copy (one 16B load per
// bilinear corner instead of two fp32 loads) -> halves gather instructions,
// bytes, and L2 lines. Producer/consumer structure = R10. offconv keeps the
// fp32 path (precision). h1 fp32 NHWC lives in d_out (read by L1 offconv,
// then overwritten by L1 dfconv's NCHW epilogue). Epilogue staging aliases
// the Bs ring (LDS 44->26 KB).
// k' = kk*256 + c. XCD swizzle: blockIdx%8 = XCD.

#define KTOT 2304
#define PXB  9216

typedef __attribute__((ext_vector_type(8))) short bf16x8;
typedef __attribute__((ext_vector_type(4))) float f32x4;

static __device__ __forceinline__ unsigned short f2bf(float f) {
    union { float f; unsigned int u; } v; v.f = f;
    unsigned int r = (v.u + 0x7FFFu + ((v.u >> 16) & 1u)) >> 16;
    return (unsigned short)r;
}
static __device__ __forceinline__ float bf2f(unsigned short h) {
    union { unsigned int u; float f; } v; v.u = ((unsigned int)h) << 16;
    return v.f;
}
// unpack 8 bf16 (uint4) -> 8 fp32; 1 bit-op per element
static __device__ __forceinline__ void unpack8(uint4 u, float* f) {
    union { unsigned int u; float f; } t;
    t.u = u.x << 16;         f[0] = t.f;
    t.u = u.x & 0xffff0000u; f[1] = t.f;
    t.u = u.y << 16;         f[2] = t.f;
    t.u = u.y & 0xffff0000u; f[3] = t.f;
    t.u = u.z << 16;         f[4] = t.f;
    t.u = u.z & 0xffff0000u; f[5] = t.f;
    t.u = u.w << 16;         f[6] = t.f;
    t.u = u.w & 0xffff0000u; f[7] = t.f;
}

// ---------------------------------------------------------------------------
// NCHW -> NHWC transpose, fp32 + bf16 outputs
// ---------------------------------------------------------------------------
__global__ __launch_bounds__(256) void transpose_kernel(const float* __restrict__ in,
                                                        float* __restrict__ outT,
                                                        unsigned short* __restrict__ outB) {
    __shared__ float tile[64][65];
    const int hw0 = blockIdx.x * 64;
    const int c0  = blockIdx.y * 64;
    const int b   = blockIdx.z;
    const int lx  = threadIdx.x & 63;
    const int ly  = threadIdx.x >> 6;
#pragma unroll
    for (int i = 0; i < 16; ++i) {
        int cl = ly + i * 4;
        tile[cl][lx] = in[(size_t)(b * 256 + c0 + cl) * PXB + hw0 + lx];
    }
    __syncthreads();
#pragma unroll
    for (int i = 0; i < 16; ++i) {
        int hwl = ly + i * 4;
        float v = tile[lx][hwl];
        size_t oi = ((size_t)b * PXB + hw0 + hwl) * 256 + c0 + lx;
        outT[oi] = v;
        outB[oi] = f2bf(v);
    }
}

// ---------------------------------------------------------------------------
// Main weight prep: w[o][c][kk] fp32 -> wA[o][k'=kk*256+c] bf16
// ---------------------------------------------------------------------------
__global__ __launch_bounds__(256) void prep_w_kernel(const float* __restrict__ w,
                                                     unsigned short* __restrict__ wA) {
    int idx = blockIdx.x * 256 + threadIdx.x;   // 256*2304
    int o = idx / KTOT;
    int k = idx - o * KTOT;
    int kk = k >> 8;
    int c  = k & 255;
    wA[idx] = f2bf(w[o * KTOT + c * 9 + kk]);
}

// ---------------------------------------------------------------------------
// Offset weight prep (split): rows 27..32 zero. hi = bf16(w), lo = bf16(w-hi).
// ---------------------------------------------------------------------------
__global__ __launch_bounds__(256) void prep_woff_kernel(const float* __restrict__ w,
                                                        unsigned short* __restrict__ wH,
                                                        unsigned short* __restrict__ wL) {
    int idx = blockIdx.x * 256 + threadIdx.x;   // 32*2304
    int o = idx / KTOT;
    int k = idx - o * KTOT;
    int kk = k >> 8;
    int c  = k & 255;
    float f = (o < 27) ? w[o * KTOT + c * 9 + kk] : 0.0f;
    unsigned short hi = f2bf(f);
    wH[idx] = hi;
    wL[idx] = f2bf(f - bf2f(hi));
}

// ---------------------------------------------------------------------------
// Fused offset conv: M=32(27) x N=64px x K=2304, split-bf16 3-term.
// Grid 288 x 512 threads; waves 0-3 K-half0, waves 4-7 K-half1. (R9 verbatim)
// ---------------------------------------------------------------------------
__global__ __launch_bounds__(512) void offconv_fused(const float* __restrict__ xt,
                                                     const unsigned short* __restrict__ AH,
                                                     const unsigned short* __restrict__ AL,
                                                     const float* __restrict__ bias,
                                                     float* __restrict__ om) {
    __shared__ __attribute__((aligned(16))) unsigned short AsH[2][32 * 72];
    __shared__ __attribute__((aligned(16))) unsigned short AsL[2][32 * 72];
    __shared__ __attribute__((aligned(16))) unsigned short BsH[2][64 * 72];
    __shared__ __attribute__((aligned(16))) unsigned short BsL[2][64 * 72];

    const int tid  = threadIdx.x;
    const int kg   = tid >> 8;
    const int tl   = tid & 255;
    const int lane = tid & 63;
    const int wq   = (tid >> 6) & 3;
    const int quad = lane >> 4, l16 = lane & 15;
    const int g    = blockIdx.x;            // 288
    const int nb   = (g & 7) * 36 + (g >> 3);
    const int n0   = nb * 64;
    const int b    = n0 / PXB;
    const int hw0  = n0 - b * PXB;

    f32x4 acc[2];
#pragma unroll
    for (int mt = 0; mt < 2; ++mt) acc[mt] = (f32x4)0.0f;

    const int arow = tl >> 3, akg = tl & 7;

    for (int it = 0; it < 18; ++it) {
        const int kt = kg * 18 + it;
        const int kk = kt >> 2, c0 = (kt & 3) * 64;
        const int dy = kk / 3 - 1, dx = kk - (kk / 3) * 3 - 1;
        __syncthreads();
        {   // stage A (32 rows x 64 k)
            size_t ai = (size_t)arow * KTOT + kt * 64 + akg * 8;
            *(uint4*)&AsH[kg][arow * 72 + akg * 8] = *(const uint4*)&AH[ai];
            *(uint4*)&AsL[kg][arow * 72 + akg * 8] = *(const uint4*)&AL[ai];
        }
        // stage B (64 px x 64 c): 2 tasks/thread per K-group
#pragma unroll
        for (int i = 0; i < 2; ++i) {
            int task = i * 256 + tl;
            int px = task >> 3, cg = task & 7;
            int hw = hw0 + px;
            int h = hw / 96, w = hw - h * 96;
            int y = h + dy, x = w + dx;
            bool valid = ((unsigned)y < 96u) && ((unsigned)x < 96u);
            float4 v0 = make_float4(0.f, 0.f, 0.f, 0.f), v1 = v0;
            if (valid) {
                const float* p = xt + ((size_t)b * PXB + y * 96 + x) * 256 + c0 + cg * 8;
                v0 = *(const float4*)p;
                v1 = *(const float4*)(p + 4);
            }
            float vals[8] = {v0.x, v0.y, v0.z, v0.w, v1.x, v1.y, v1.z, v1.w};
            unsigned short hi[8], lo[8];
#pragma unroll
            for (int j = 0; j < 8; ++j) {
                hi[j] = f2bf(vals[j]);
                lo[j] = f2bf(vals[j] - bf2f(hi[j]));
            }
            *(uint4*)&BsH[kg][px * 72 + cg * 8] = *(uint4*)hi;
            *(uint4*)&BsL[kg][px * 72 + cg * 8] = *(uint4*)lo;
        }
        __syncthreads();
#pragma unroll
        for (int ks = 0; ks < 2; ++ks) {
            bf16x8 ah[2], al[2], bh, bl;
#pragma unroll
            for (int mt = 0; mt < 2; ++mt) {
                ah[mt] = *(const bf16x8*)&AsH[kg][(mt * 16 + l16) * 72 + ks * 32 + quad * 8];
                al[mt] = *(const bf16x8*)&AsL[kg][(mt * 16 + l16) * 72 + ks * 32 + quad * 8];
            }
            bh = *(const bf16x8*)&BsH[kg][(wq * 16 + l16) * 72 + ks * 32 + quad * 8];
            bl = *(const bf16x8*)&BsL[kg][(wq * 16 + l16) * 72 + ks * 32 + quad * 8];
#pragma unroll
            for (int mt = 0; mt < 2; ++mt) {
                acc[mt] = __builtin_amdgcn_mfma_f32_16x16x32_bf16(ah[mt], bh, acc[mt], 0, 0, 0);
                acc[mt] = __builtin_amdgcn_mfma_f32_16x16x32_bf16(ah[mt], bl, acc[mt], 0, 0, 0);
                acc[mt] = __builtin_amdgcn_mfma_f32_16x16x32_bf16(al[mt], bh, acc[mt], 0, 0, 0);
            }
        }
    }

    // ---- in-block split-K reduction: kg1 publishes, kg0 adds + stores ----
    float* red = (float*)BsH;
    __syncthreads();
    if (kg == 1) {
#pragma unroll
        for (int mt = 0; mt < 2; ++mt)
#pragma unroll
            for (int r = 0; r < 4; ++r)
                red[wq * 512 + mt * 256 + quad * 64 + r * 16 + l16] = acc[mt][r];
    }
    __syncthreads();
    if (kg == 0) {
#pragma unroll
        for (int mt = 0; mt < 2; ++mt)
#pragma unroll
            for (int r = 0; r < 4; ++r) {
                float v = acc[mt][r] + red[wq * 512 + mt * 256 + quad * 64 + r * 16 + l16];
                int m = mt * 16 + quad * 4 + r;
                int n = wq * 16 + l16;
                if (m < 27)
                    om[(size_t)(b * 27 + m) * PXB + hw0 + n] = v + bias[m];
            }
    }
}

// ---------------------------------------------------------------------------
// Fused deformable conv, producer/consumer: M=256 x N=32px, K=2304.
// Grid 576 x 512 thr. Waves 0-3 gather (bf16 source, 4x16B loads/cell) into
// a 4-deep LDS ring; waves 4-7 consume with MFMA (A direct from L2).
// out_mode 0: NCHW fp32. out_mode 1: NHWC fp32 (outT) + NHWC bf16 (outB).
// ---------------------------------------------------------------------------
__global__ __launch_bounds__(512) void dfconv_fused(const unsigned short* __restrict__ xtb,
                                                    const float* __restrict__ om,
                                                    const unsigned short* __restrict__ A,
                                                    float* __restrict__ out,
                                                    unsigned short* __restrict__ outB,
                                                    int out_mode) {
    __shared__ __attribute__((aligned(16))) unsigned short Bs[4][32 * 72]; // ring 18.4 KB
    __shared__ __attribute__((aligned(16))) unsigned short goff[288 * 4];
    __shared__ __attribute__((aligned(16))) float gwt[288 * 4];
    __shared__ int ready[4];
    __shared__ int done[4];

    const int tid  = threadIdx.x;
    const int wv   = tid >> 6;
    const int lane = tid & 63;
    const int quad = lane >> 4, l16 = lane & 15;
    // XCD swizzle: g%8 = xcd owns n-blocks [xcd*72, xcd*72+72)
    const int g    = blockIdx.x;            // 576
    const int nb   = (g & 7) * 72 + (g >> 3);
    const int n0   = nb * 32;
    const int b    = n0 / PXB;
    const int hw0  = n0 - b * PXB;

    if (tid < 4) { ready[tid] = 0; done[tid] = 0; }

    // ---- geometry: 32 px x 9 taps ----
    if (tid < 288) {
        int task = tid;
        int px = task / 9;
        int kk = task - px * 9;
        int hw = hw0 + px;
        int h = hw / 96, w = hw - h * 96;
        const float* omp = om + (size_t)b * 27 * PXB + hw;
        float dyv = omp[(size_t)(2 * kk) * PXB];
        float dxv = omp[(size_t)(2 * kk + 1) * PXB];
        float mv  = omp[(size_t)(18 + kk) * PXB];
        float mk  = 1.0f / (1.0f + __expf(-mv));

        float ys = (float)(h + (kk / 3) - 1) + dyv;
        float xs = (float)(w + (kk - (kk / 3) * 3) - 1) + dxv;
        float fy = floorf(ys), fx = floorf(xs);
        int iy = (int)fy, ix = (int)fx;
        float wy1 = ys - fy, wx1 = xs - fx;
        float wy0 = 1.0f - wy1, wx0 = 1.0f - wx1;
        bool yv0 = (unsigned)iy < 96u, yv1 = (unsigned)(iy + 1) < 96u;
        bool xv0 = (unsigned)ix < 96u, xv1 = (unsigned)(ix + 1) < 96u;
        int y0 = min(max(iy, 0), 95),     y1 = min(max(iy + 1, 0), 95);
        int x0 = min(max(ix, 0), 95),     x1 = min(max(ix + 1, 0), 95);
        int gg = task * 4;
        goff[gg + 0] = (unsigned short)(y0 * 96 + x0);
        goff[gg + 1] = (unsigned short)(y0 * 96 + x1);
        goff[gg + 2] = (unsigned short)(y1 * 96 + x0);
        goff[gg + 3] = (unsigned short)(y1 * 96 + x1);
        gwt[gg + 0] = (yv0 && xv0) ? mk * wy0 * wx0 : 0.0f;
        gwt[gg + 1] = (yv0 && xv1) ? mk * wy0 * wx1 : 0.0f;
        gwt[gg + 2] = (yv1 && xv0) ? mk * wy1 * wx0 : 0.0f;
        gwt[gg + 3] = (yv1 && xv1) ? mk * wy1 * wx1 : 0.0f;
    }
    __syncthreads();   // geometry + flags visible

    volatile int* vready = ready;
    volatile int* vdone  = done;

    f32x4 acc[4][2];
#pragma unroll
    for (int mt = 0; mt < 4; ++mt) { acc[mt][0] = (f32x4)0.0f; acc[mt][1] = (f32x4)0.0f; }

    if (wv < 4) {
        // ================= PRODUCERS (waves 0-3) =================
        const int pl = wv * 64 + lane;      // 0..255: cell id
        const int px = pl >> 3, cg = pl & 7;
        const unsigned short* xbase = xtb + (size_t)b * PXB * 256 + cg * 8;

        for (int kt = 0; kt < 36; ++kt) {
            const int st = kt & 3, rr = kt >> 2;
            const int tap = kt >> 2, c0 = (kt & 3) * 64;
            // issue 4 corner loads (16B each = 8 bf16 channels) first
            int gg = (px * 9 + tap) * 4;
            ushort4 o4 = *(const ushort4*)&goff[gg];
            float4  wt = *(const float4*)&gwt[gg];
            const unsigned short* cb = xbase + c0;
            uint4 u0 = *(const uint4*)(cb + (size_t)o4.x * 256);
            uint4 u1 = *(const uint4*)(cb + (size_t)o4.y * 256);
            uint4 u2 = *(const uint4*)(cb + (size_t)o4.z * 256);
            uint4 u3 = *(const uint4*)(cb + (size_t)o4.w * 256);
            // wait for consumers to release this slot (round rr-1)
            const int tgt = 4 * rr;
            while (vdone[st] < tgt) __builtin_amdgcn_s_sleep(1);
            // unpack + interp + convert + write panel
            float f0[8], f1[8], f2[8], f3[8];
            unpack8(u0, f0); unpack8(u1, f1); unpack8(u2, f2); unpack8(u3, f3);
            unsigned short res[8];
#pragma unroll
            for (int j = 0; j < 8; ++j)
                res[j] = f2bf(wt.x * f0[j] + wt.y * f1[j] + wt.z * f2[j] + wt.w * f3[j]);
            *(uint4*)&Bs[st][px * 72 + cg * 8] = *(uint4*)res;
            __threadfence_block();
            if (lane == 0) atomicAdd(&ready[st], 1);
        }
    } else {
        // ================= CONSUMERS (waves 4-7) =================
        const int mq = wv - 4;
        const unsigned short* Arow = A + (size_t)(mq * 64 + l16) * KTOT + quad * 8;

        for (int kt = 0; kt < 36; ++kt) {
            const int st = kt & 3, rr = kt >> 2;
            bf16x8 af[2][4];
#pragma unroll
            for (int ks = 0; ks < 2; ++ks)
#pragma unroll
                for (int mt = 0; mt < 4; ++mt)
                    af[ks][mt] = *(const bf16x8*)(Arow + (size_t)(mt * 16) * KTOT + kt * 64 + ks * 32);
            const int tgt = 4 * (rr + 1);
            while (vready[st] < tgt) __builtin_amdgcn_s_sleep(1);
#pragma unroll
            for (int ks = 0; ks < 2; ++ks) {
                bf16x8 bfr[2];
#pragma unroll
                for (int nt = 0; nt < 2; ++nt)
                    bfr[nt] = *(const bf16x8*)&Bs[st][(nt * 16 + l16) * 72 + ks * 32 + quad * 8];
#pragma unroll
                for (int mt = 0; mt < 4; ++mt)
#pragma unroll
                    for (int nt = 0; nt < 2; ++nt)
                        acc[mt][nt] = __builtin_amdgcn_mfma_f32_16x16x32_bf16(
                            af[ks][mt], bfr[nt], acc[mt][nt], 0, 0, 0);
            }
            __threadfence_block();
            if (lane == 0) atomicAdd(&done[st], 1);
        }
    }

    __syncthreads();   // join for epilogue

    // ---- epilogues: staging aliases the Bs ring ----
    float* tileS = (float*)Bs;   // 18432 B
    if (out_mode == 0) {
        // NCHW out[b][m][hw0..+31]: 2 passes of 128 m; tileS[128][36]
#pragma unroll
        for (int pass = 0; pass < 2; ++pass) {
            if (wv >= 4 && (wv - 4) >> 1 == pass) {
                int mqh = (wv - 4) & 1;
#pragma unroll
                for (int mt = 0; mt < 4; ++mt)
#pragma unroll
                    for (int nt = 0; nt < 2; ++nt)
#pragma unroll
                        for (int r = 0; r < 4; ++r) {
                            int ml = mqh * 64 + mt * 16 + quad * 4 + r;   // 0..127
                            int n  = nt * 16 + l16;                        // 0..31
                            tileS[ml * 36 + n] = fmaxf(acc[mt][nt][r], 0.0f);
                        }
            }
            __syncthreads();
#pragma unroll
            for (int j = 0; j < 2; ++j) {
                int idx = j * 512 + tid;          // 1024 float4s = 128m x 8q
                int row = idx >> 3, q = idx & 7;
                int m = pass * 128 + row;
                *(float4*)&out[(size_t)(b * 256 + m) * PXB + hw0 + q * 4] =
                    *(const float4*)&tileS[row * 36 + q * 4];
            }
            __syncthreads();
        }
    } else {
        // NHWC fp32 (outT in `out`) + NHWC bf16 (outB): 2 passes of 16 px.
#pragma unroll
        for (int pass = 0; pass < 2; ++pass) {
            if (wv >= 4) {
                int mq = wv - 4;
#pragma unroll
                for (int mt = 0; mt < 4; ++mt) {
                    f32x4 v = acc[mt][pass];
                    v[0] = fmaxf(v[0], 0.f); v[1] = fmaxf(v[1], 0.f);
                    v[2] = fmaxf(v[2], 0.f); v[3] = fmaxf(v[3], 0.f);
                    *(f32x4*)&tileS[l16 * 264 + mq * 64 + mt * 16 + quad * 4] = v;
                }
            }
            __syncthreads();
#pragma unroll
            for (int j = 0; j < 2; ++j) {
                int idx = j * 512 + tid;          // 1024 float4s = 16px x 64
                int pxl = idx >> 6, ln = idx & 63;
                float4 v = *(const float4*)&tileS[pxl * 264 + ln * 4];
                size_t oi = ((size_t)b * PXB + hw0 + pass * 16 + pxl) * 256 + ln * 4;
                *(float4*)&out[oi] = v;
                unsigned short bv[4] = {f2bf(v.x), f2bf(v.y), f2bf(v.z), f2bf(v.w)};
                *(ushort4*)&outB[oi] = *(ushort4*)bv;
            }
            __syncthreads();
        }
    }
}

// ---------------------------------------------------------------------------
extern "C" void kernel_launch(void* const* d_in, const int* in_sizes, int n_in,
                              void* d_out, int out_size, void* d_ws, size_t ws_size,
                              hipStream_t stream) {
    const float* x     = (const float*)d_in[0];
    const float* woff0 = (const float*)d_in[1];
    const float* boff0 = (const float*)d_in[2];
    const float* w0    = (const float*)d_in[3];
    const float* woff1 = (const float*)d_in[4];
    const float* boff1 = (const float*)d_in[5];
    const float* w1    = (const float*)d_in[6];
    float* out = (float*)d_out;

    char* p = (char*)d_ws;
    float* om  = (float*)p;  p += (size_t)2 * 27 * PXB * 4;               // 2.0 MB
    float* xt  = (float*)p;  p += (size_t)2 * 256 * PXB * 4;              // 18.9 MB (fp32 NHWC)
    unsigned short* xtb = (unsigned short*)p; p += (size_t)2 * 256 * PXB * 2;  // 9.4 MB (bf16 NHWC)
    unsigned short* h1b = (unsigned short*)p; p += (size_t)2 * 256 * PXB * 2;  // 9.4 MB (bf16 NHWC)
    unsigned short* wA0 = (unsigned short*)p; p += (size_t)256 * KTOT * 2;
    unsigned short* wA1 = (unsigned short*)p; p += (size_t)256 * KTOT * 2;
    unsigned short* wH0 = (unsigned short*)p; p += (size_t)32 * KTOT * 2;
    unsigned short* wL0 = (unsigned short*)p; p += (size_t)32 * KTOT * 2;
    unsigned short* wH1 = (unsigned short*)p; p += (size_t)32 * KTOT * 2;
    unsigned short* wL1 = (unsigned short*)p; p += (size_t)32 * KTOT * 2;

    // h1 fp32 NHWC lives in d_out: written by L0 dfconv epilogue, read by L1
    // offconv, then overwritten (NCHW) by L1 dfconv — lifetimes are disjoint.
    float* h1t = out;

    hipLaunchKernelGGL(transpose_kernel, dim3(PXB / 64, 4, 2), dim3(256), 0, stream, x, xt, xtb);
    hipLaunchKernelGGL(prep_w_kernel, dim3(256 * KTOT / 256), dim3(256), 0, stream, w0, wA0);
    hipLaunchKernelGGL(prep_w_kernel, dim3(256 * KTOT / 256), dim3(256), 0, stream, w1, wA1);
    hipLaunchKernelGGL(prep_woff_kernel, dim3(32 * KTOT / 256), dim3(256), 0, stream, woff0, wH0, wL0);
    hipLaunchKernelGGL(prep_woff_kernel, dim3(32 * KTOT / 256), dim3(256), 0, stream, woff1, wH1, wL1);

    // Layer 0: x -> h1 (NHWC fp32 in d_out + bf16 in h1b)
    hipLaunchKernelGGL(offconv_fused, dim3(288), dim3(512), 0, stream, xt, wH0, wL0, boff0, om);
    hipLaunchKernelGGL(dfconv_fused, dim3(576), dim3(512), 0, stream, xtb, om, wA0, h1t, h1b, 1);

    // Layer 1: h1 -> out (NCHW fp32)
    hipLaunchKernelGGL(offconv_fused, dim3(288), dim3(512), 0, stream, h1t, wH1, wL1, boff1, om);
    hipLaunchKernelGGL(dfconv_fused, dim3(576), dim3(512), 0, stream, h1b, om, wA1, out, (unsigned short*)nullptr, 0);
}